// Round 6
// baseline (295.253 us; speedup 1.0000x reference)
//
#include <hip/hip_runtime.h>
#include <math.h>

// Problem constants (NomicBertAttention): B=2, S=4096, DM=768, H=12, HD=64
#define B_   2
#define S_   4096
#define DM_  768
#define H_   12
#define HD_  64
#define M_   (B_ * S_)                 // 8192 rows
#define ROWELEMS ((size_t)M_ * DM_)    // 6291456 elems per [M,DM] buffer
#define WELEMS  ((size_t)DM_ * DM_)    // 589824 elems per weight

// net softmax scale: SCALING*SCALING = 1/64, times log2(e) so v_exp_f32 (2^x)
// computes e^(score/64) directly.  Folded into Q in the QKV-GEMM epilogue.
#define QSC (1.4426950408889634f / 64.0f)

typedef unsigned short u16;
typedef unsigned int   u32;
typedef __attribute__((ext_vector_type(8))) short  short8;   // 8 x bf16 (4 VGPR)
typedef __attribute__((ext_vector_type(4))) float  floatx4;  // MFMA accumulator
typedef __attribute__((ext_vector_type(4))) u32    uint32x4;

__device__ inline u16 f2bf(float f) {                 // RNE round
    u32 u = __builtin_bit_cast(u32, f);
    u += 0x7FFF + ((u >> 16) & 1);
    return (u16)(u >> 16);
}
__device__ inline float bf2f(u16 h) {
    return __builtin_bit_cast(float, (u32)h << 16);
}
__device__ inline u32 pk_trunc(float a, float b) {    // [bf16(b)<<16 | bf16(a)], truncate
    return __builtin_amdgcn_perm(__builtin_bit_cast(u32, b),
                                 __builtin_bit_cast(u32, a), 0x07060302);
}

// XOR-swizzled LDS offset, pitch 64 bf16 (128 B) rows:
// element (r, c) lives at r*64 + ((c/8 ^ (r&7))*8) + c%8.
__device__ inline int sw_off(int r, int cg) {         // cg = c>>3 (8-elem group)
    return (r << 6) + ((cg ^ (r & 7)) << 3);
}

// Async global->LDS 16B DMA (global_load_lds_dwordx4). LDS dest is
// wave-uniform base + lane*16; we permute the per-lane GLOBAL address so the
// content lands in the swizzled layout (same 128B lines -> still coalesced).
__device__ __forceinline__ void load_lds16(const u16* g, u16* l) {
    __builtin_amdgcn_global_load_lds(
        (const __attribute__((address_space(1))) u32*)g,
        (__attribute__((address_space(3))) u32*)l, 16, 0, 0);
}

// Explicit vmcnt(0) drain: simm16 = lgkmcnt(15)|expcnt(7)|vmcnt(0) = 0xF70.
// R11 failed post-timing validation with a timing-dependent divergence; the
// DMA->barrier visibility must not depend on the compiler's barrier lowering
// emitting the vmcnt drain. R12 confirmed this fixes it at zero cost.
__device__ __forceinline__ void drain_vm() {
    __builtin_amdgcn_s_waitcnt(0x0F70);
}

// =====================================================================
// fp32 -> bf16 conversion: y=0 hidden [M,DM]; y=1..4 weights [DM,DM]
// =====================================================================
__global__ __launch_bounds__(256) void conv_bf16(
    const float* __restrict__ h,  const float* __restrict__ wq,
    const float* __restrict__ wk, const float* __restrict__ wv,
    const float* __restrict__ wo, u16* __restrict__ hb, u16* __restrict__ wb)
{
    const int y = blockIdx.y;
    const float* src; u16* dst; size_t n4;
    if (y == 0)      { src = h;  dst = hb;              n4 = ROWELEMS / 4; }
    else if (y == 1) { src = wq; dst = wb;              n4 = WELEMS / 4; }
    else if (y == 2) { src = wk; dst = wb + WELEMS;     n4 = WELEMS / 4; }
    else if (y == 3) { src = wv; dst = wb + 2 * WELEMS; n4 = WELEMS / 4; }
    else             { src = wo; dst = wb + 3 * WELEMS; n4 = WELEMS / 4; }
    const size_t stride = (size_t)gridDim.x * 256;
    for (size_t i = blockIdx.x * 256 + threadIdx.x; i < n4; i += stride) {
        float4 v = *(const float4*)&src[i * 4];
        u32 p0 = (u32)f2bf(v.x) | ((u32)f2bf(v.y) << 16);
        u32 p1 = (u32)f2bf(v.z) | ((u32)f2bf(v.w) << 16);
        *(uint2*)&dst[i * 4] = make_uint2(p0, p1);
    }
}

// =====================================================================
// Fused QKV GEMM + RoPE + head-major repack.
// 128x128 tile, BK=64, 2x2 waves, 16x16x32 MFMA, global_load_lds staging
// into swizzled LDS.
// Epilogue z=0/1: rope -> PAIR-INTERLEAVED Qh/Kh rows (u32 slot hd1 holds
// the rotated pair (hd1, hd1+32)); dot products are invariant under a
// fixed permutation applied to BOTH Q and K rows, so flash is unchanged.
// Epilogue z=2: transpose -> Vt[B,H,HD,S].
// =====================================================================
__global__ __launch_bounds__(256, 3) void gemm_qkv(
    const u16* __restrict__ A,
    const u16* __restrict__ W0, const u16* __restrict__ W1, const u16* __restrict__ W2,
    const float* __restrict__ b0, const float* __restrict__ b1, const float* __restrict__ b2,
    const float* __restrict__ cosT, const float* __restrict__ sinT,
    u16* __restrict__ Qh, u16* __restrict__ Kh, u16* __restrict__ Vt)
{
    __shared__ __align__(16) u16 As[128 * 64];   // 16 KB, swizzled
    __shared__ __align__(16) u16 Ws[128 * 64];   // 16 KB, swizzled

    const int tid  = threadIdx.x;
    const int wave = tid >> 6, lane = tid & 63;
    const int n16  = lane & 15, quad = lane >> 4;
    const int wm   = wave >> 1, wn = wave & 1;
    const int m0   = blockIdx.y * 128, n0 = blockIdx.x * 128;
    const int z    = blockIdx.z;

    const u16* Wz = (z == 0) ? W0 : (z == 1) ? W1 : W2;
    const float* bz = (z == 0) ? b0 : (z == 1) ? b1 : b2;

    // staging lane constants: granule g covers (r, content-group cg = slot^(r&7))
    int gao[4], ldso[4];
#pragma unroll
    for (int i = 0; i < 4; i++) {
        int g = wave * 256 + i * 64 + lane;      // 0..1023
        int r = g >> 3, cg = (g & 7) ^ (r & 7);
        gao[i]  = r * DM_ + cg * 8;
        ldso[i] = (wave * 256 + i * 64) * 8;
    }
    const u16* Ap = A  + (size_t)m0 * DM_;
    const u16* Wp = Wz + (size_t)n0 * DM_;

    floatx4 acc[4][4];
#pragma unroll
    for (int i = 0; i < 4; i++)
#pragma unroll
        for (int j = 0; j < 4; j++) acc[i][j] = (floatx4){0.f, 0.f, 0.f, 0.f};

    for (int k0 = 0; k0 < DM_; k0 += 64) {
        __syncthreads();                          // prev tile fully read
#pragma unroll
        for (int i = 0; i < 4; i++) {
            load_lds16(Ap + k0 + gao[i], &As[ldso[i]]);
            load_lds16(Wp + k0 + gao[i], &Ws[ldso[i]]);
        }
        drain_vm();                               // DMA data LDS-visible
        __syncthreads();                          // tile landed for ALL waves
#pragma unroll
        for (int ks = 0; ks < 2; ks++) {
            short8 af[4], bf[4];
#pragma unroll
            for (int t = 0; t < 4; t++) {
                af[t] = *(const short8*)&As[sw_off(wm * 64 + t * 16 + n16, ks * 4 + quad)];
                bf[t] = *(const short8*)&Ws[sw_off(wn * 64 + t * 16 + n16, ks * 4 + quad)];
            }
#pragma unroll
            for (int i = 0; i < 4; i++)
#pragma unroll
                for (int j = 0; j < 4; j++)
                    acc[i][j] = __builtin_amdgcn_mfma_f32_16x16x32_bf16(
                        af[i], bf[j], acc[i][j], 0, 0, 0);
        }
    }

    // ---- epilogue: C/D layout col = n16, row = quad*4+r ----
    if (z == 2) {
#pragma unroll
        for (int i = 0; i < 4; i++)
#pragma unroll
            for (int j = 0; j < 4; j++) {
                const int col = n0 + wn * 64 + j * 16 + n16;
                const int h = col >> 6, hd = col & 63;
                const int row0 = m0 + wm * 64 + i * 16 + quad * 4;
                const int b = row0 >> 12, s0 = row0 & 4095;
                const float bias = bz[col];
                float v0 = acc[i][j][0] + bias, v1 = acc[i][j][1] + bias;
                float v2 = acc[i][j][2] + bias, v3 = acc[i][j][3] + bias;
                u32 w0 = (u32)f2bf(v0) | ((u32)f2bf(v1) << 16);
                u32 w1 = (u32)f2bf(v2) | ((u32)f2bf(v3) << 16);
                *(uint2*)&Vt[((size_t)(b * H_ + h) * HD_ + hd) * S_ + s0] = make_uint2(w0, w1);
            }
    } else {
        u32* Out32 = (u32*)((z == 0) ? Qh : Kh);
        const float sc_ = (z == 0) ? QSC : 1.0f;
#pragma unroll
        for (int i = 0; i < 4; i++)
#pragma unroll
            for (int j = 0; j < 2; j++) {
                const int col1 = n0 + wn * 64 + j * 16 + n16;   // hd1 < 32
                const int col2 = col1 + 32;
                const int h = col1 >> 6, hd1 = col1 & 63;       // hd1 in [0,32)
                const float bias1 = bz[col1], bias2 = bz[col2];
#pragma unroll
                for (int r = 0; r < 4; r++) {
                    const int row = m0 + wm * 64 + i * 16 + quad * 4 + r;
                    const int b = row >> 12, s = row & 4095;
                    const float c  = cosT[s * HD_ + hd1];
                    const float sn = sinT[s * HD_ + hd1];
                    const float x1 = acc[i][j][r] + bias1;
                    const float x2 = acc[i][j + 2][r] + bias2;
                    const float y1 = (x1 * c - x2 * sn) * sc_;
                    const float y2 = (x2 * c + x1 * sn) * sc_;
                    // pair-interleaved: u32 slot hd1 of the 32-u32 row
                    Out32[(((size_t)(b * H_ + h) * S_ + s) << 5) + hd1] =
                        (u32)f2bf(y1) | ((u32)f2bf(y2) << 16);
                }
            }
    }
}

// =====================================================================
// Flash attention, bf16 MFMA, static softmax.
// grid (S/128, B*H) = 768 blocks; block = 128 q-rows, 4 waves.
//
// R18: rt=4 + INTRA-BLOCK KV-SPLIT (post-mortem of R17).  R17's win
// (Ps round-trip deleted, bank conflicts -> 0) left K/V fragment
// ds_reads as the floor: 12 waves/CU x 64 iters x 16 ds_read_b128
// ~= 147k of 261k per-CU cycles (~56% LDS busy), because a wave reads
// the full 16KB K+V tile per iter but amortizes it over only 32 q-rows
// (36 MFMA).  Fix: each wave owns 64 q-rows (rt=4) and sweeps HALF the
// KV range -- static softmax means l and O are pure sums, so KV-range
// splitting is exact.  wave = (qhalf, kvhalf); two concurrent tile
// streams in LDS (32 KB); 32 iters; same 16 reads/wave-iter now feed
// 72 MFMA -> per-CU LDS demand halves (147k -> 74k cyc), barrier/drain
// events halve, MFMA/VALU totals unchanged.  Partials combined once at
// the end through the (then-dead) KV LDS.
//
// rho row-permutation + in-register pa packing carried from R17
// unchanged (per-tile property, independent of rt):
//   K staged with row shuffle rho (bits b4<-b3, b3<-b2, b2<-b4), so
//   lane (n16,quad)'s S^T values ARE its PV A-fragment slots:
//   pa[rt][ks] = {pk(sct[2ks][rt]), pk(sct[2ks+1][rt])}.
//
// __launch_bounds__(256,2): VGPR cap 256 (est. ~220 peak: qf 32 +
// o_acc 64 + o_l 16 + sct 64 transient + pa/kf/vb).  2 blocks/CU.
// DO NOT raise: R10 showed a forced-low cap -> scratch spill disaster.
// =====================================================================
__global__ __launch_bounds__(256, 2) void flash_mfma(
    const u16* __restrict__ Qh, const u16* __restrict__ Kh,
    const u16* __restrict__ Vt, u16* __restrict__ O)
{
    // bytes: [0,8K) Ks0 | [8K,16K) Vs0 | [16K,24K) Ks1 | [24K,32K) Vs1
    // epilogue reuse: [0,32K) O-partials (f32), [32K,32.5K) l-partials
    __shared__ __align__(16) u16 SMEM[16640];     // 33280 B

    const int tid  = threadIdx.x;
    const int wave = tid >> 6, lane = tid & 63;
    const int n16  = lane & 15, quad = lane >> 4;
    const int kvh  = wave & 1;                    // KV half this wave sweeps
    const int qh   = wave >> 1;                   // Q half this wave owns
    const int qt   = blockIdx.x;
    const int bh   = blockIdx.y;
    const size_t qk_base = (size_t)bh * S_ * HD_;
    const size_t vt_base = (size_t)bh * HD_ * S_;
    const int q0   = qt * 128;

    // Q fragments in registers (A/B frag layout: lane&15 x (quad*8+j))
    short8 qf[4][2];
#pragma unroll
    for (int rt = 0; rt < 4; rt++)
#pragma unroll
        for (int ks = 0; ks < 2; ks++)
            qf[rt][ks] = *(const short8*)&Qh[qk_base +
                (size_t)(q0 + qh * 64 + rt * 16 + n16) * HD_ + ks * 32 + quad * 8];

    short8 ones;
#pragma unroll
    for (int j = 0; j < 8; j++) ones[j] = (short)0x3F80;   // bf16 1.0

    // staging lane constants (swizzled global addresses).
    // K rows permuted by rho: LDS named row n holds physical K row rho(n).
    int gk_off[2], gv_off[2], ldso[2];
#pragma unroll
    for (int i = 0; i < 2; i++) {
        int g = wave * 128 + i * 64 + lane;       // 0..511
        int r = g >> 3, cg = (g & 7) ^ (r & 7);
        int rk = (r & 0x23) | ((r & 8) << 1) | ((r & 4) << 1) | ((r & 16) >> 2);
        gk_off[i] = rk * HD_ + cg * 8;
        gv_off[i] = r  * S_  + cg * 8;
        ldso[i]   = (wave * 128 + i * 64) * 8;
    }

    floatx4 o_acc[4][4];
    floatx4 o_l[4];                   // l accumulator (ones-MFMA, C-layout)
#pragma unroll
    for (int rt = 0; rt < 4; rt++) {
        o_l[rt] = (floatx4){0.f, 0.f, 0.f, 0.f};
#pragma unroll
        for (int dt = 0; dt < 4; dt++) o_acc[rt][dt] = (floatx4){0.f, 0.f, 0.f, 0.f};
    }

    const u16* Kg = Kh + qk_base;                 // stream0; stream1 at +32*64*HD
    const u16* Vg = Vt + vt_base;                 // stream0; stream1 at +32*64

    u16* Ksb = &SMEM[kvh * 8192];                 // this wave's K tile
    u16* Vsb = &SMEM[kvh * 8192 + 4096];          // this wave's V tile

    for (int it = 0; it < 32; it++) {
        __syncthreads();                          // prev tiles fully read
#pragma unroll
        for (int i = 0; i < 2; i++) {
            load_lds16(Kg + gk_off[i],               &SMEM[ldso[i]]);           // Ks0
            load_lds16(Vg + gv_off[i],               &SMEM[4096  + ldso[i]]);   // Vs0
            load_lds16(Kg + 32 * 64 * HD_ + gk_off[i], &SMEM[8192  + ldso[i]]); // Ks1
            load_lds16(Vg + 32 * 64 + gv_off[i],     &SMEM[12288 + ldso[i]]);   // Vs1
        }
        drain_vm();                               // DMA data LDS-visible
        __syncthreads();                          // tiles landed for ALL waves
        Kg += 64 * HD_;
        Vg += 64;

        // ---- S^T = K Q^T : D[m=named kcol][n=qrow] ----
        floatx4 sct[4][4];
#pragma unroll
        for (int ct = 0; ct < 4; ct++)
#pragma unroll
            for (int rt = 0; rt < 4; rt++)
                sct[ct][rt] = (floatx4){0.f, 0.f, 0.f, 0.f};
#pragma unroll
        for (int ks = 0; ks < 2; ks++) {
            short8 kf[4];
#pragma unroll
            for (int ct = 0; ct < 4; ct++)
                kf[ct] = *(const short8*)&Ksb[sw_off(ct * 16 + n16, ks * 4 + quad)];
#pragma unroll
            for (int ct = 0; ct < 4; ct++)
#pragma unroll
                for (int rt = 0; rt < 4; rt++)
                    sct[ct][rt] = __builtin_amdgcn_mfma_f32_16x16x32_bf16(
                        kf[ct], qf[rt][ks], sct[ct][rt], 0, 0, 0);
        }

        // ---- P = exp2(S^T), packed IN-REGISTER into PV A-fragments ----
        short8 pa[4][2];
#pragma unroll
        for (int rt = 0; rt < 4; rt++)
#pragma unroll
            for (int ks = 0; ks < 2; ks++) {
                const floatx4 lo = sct[2 * ks][rt];
                const floatx4 hi = sct[2 * ks + 1][rt];
                uint32x4 w;
                w[0] = pk_trunc(__builtin_amdgcn_exp2f(lo[0]),
                                __builtin_amdgcn_exp2f(lo[1]));
                w[1] = pk_trunc(__builtin_amdgcn_exp2f(lo[2]),
                                __builtin_amdgcn_exp2f(lo[3]));
                w[2] = pk_trunc(__builtin_amdgcn_exp2f(hi[0]),
                                __builtin_amdgcn_exp2f(hi[1]));
                w[3] = pk_trunc(__builtin_amdgcn_exp2f(hi[2]),
                                __builtin_amdgcn_exp2f(hi[3]));
                pa[rt][ks] = __builtin_bit_cast(short8, w);
            }

        // ---- O += P V ; l += P * ones (matrix pipe) ----
#pragma unroll
        for (int ks = 0; ks < 2; ks++) {
            short8 vb[4];
#pragma unroll
            for (int dt = 0; dt < 4; dt++)
                vb[dt] = *(const short8*)&Vsb[sw_off(dt * 16 + n16, ks * 4 + quad)];
#pragma unroll
            for (int rt = 0; rt < 4; rt++) {
#pragma unroll
                for (int dt = 0; dt < 4; dt++)
                    o_acc[rt][dt] = __builtin_amdgcn_mfma_f32_16x16x32_bf16(
                        pa[rt][ks], vb[dt], o_acc[rt][dt], 0, 0, 0);
                o_l[rt] = __builtin_amdgcn_mfma_f32_16x16x32_bf16(
                    pa[rt][ks], ones, o_l[rt], 0, 0, 0);
            }
        }
    }

    // ---- combine KV-halves through LDS, normalize, write ----
    __syncthreads();                              // all KV reads done; SMEM reusable
    float* Op = (float*)SMEM;                     // [2][64][64]
    float* lp = (float*)&SMEM[16384];             // [2][64]
    if (kvh == 1) {
#pragma unroll
        for (int rt = 0; rt < 4; rt++)
#pragma unroll
            for (int r = 0; r < 4; r++) {
                const int row = rt * 16 + quad * 4 + r;
                if (n16 == 0) lp[qh * 64 + row] = o_l[rt][r];
#pragma unroll
                for (int dt = 0; dt < 4; dt++)
                    Op[qh * 4096 + row * 64 + dt * 16 + n16] = o_acc[rt][dt][r];
            }
    }
    __syncthreads();
    if (kvh == 0) {
        const int b = bh / H_, h = bh % H_;
#pragma unroll
        for (int rt = 0; rt < 4; rt++)
#pragma unroll
            for (int r = 0; r < 4; r++) {
                const int row = rt * 16 + quad * 4 + r;
                const float lsum = o_l[rt][r] + lp[qh * 64 + row];
                const float inv  = 1.0f / lsum;
                const int srow = q0 + qh * 64 + row;
                u16* Orow = O + ((size_t)b * S_ + srow) * DM_ + h * HD_;
#pragma unroll
                for (int dt = 0; dt < 4; dt++) {
                    const float v = o_acc[rt][dt][r] +
                                    Op[qh * 4096 + row * 64 + dt * 16 + n16];
                    Orow[dt * 16 + n16] = f2bf(v * inv);
                }
            }
    }
}

// =====================================================================
// Out-proj GEMM, pure DMA-staged (R14: flash output is pre-normalized):
//   out = A @ Wo^T + hidden (fp32).  A and W both via global_load_lds.
// Tile 64(m) x 128(n), BK=64, 2x2 waves (wave: 32 rows x 64 cols).
// =====================================================================
__global__ __launch_bounds__(256, 4) void gemm_out(
    const u16* __restrict__ A, const u16* __restrict__ W,
    const float* __restrict__ resid, float* __restrict__ Cf)
{
    __shared__ __align__(16) u16 As[64 * 64];     //  8 KB, swizzled
    __shared__ __align__(16) u16 Ws[128 * 64];    // 16 KB, swizzled

    const int tid  = threadIdx.x;
    const int wave = tid >> 6, lane = tid & 63;
    const int n16  = lane & 15, quad = lane >> 4;
    const int wm   = wave >> 1, wn = wave & 1;
    const int m0   = blockIdx.y * 64, n0 = blockIdx.x * 128;

    // W: 1024 granules (4 DMA/thread); A: 512 granules (2 DMA/thread)
    int gwo[4], ldswo[4], gao[2], ldsao[2];
#pragma unroll
    for (int i = 0; i < 4; i++) {
        int g = wave * 256 + i * 64 + lane;
        int r = g >> 3, cg = (g & 7) ^ (r & 7);
        gwo[i]   = r * DM_ + cg * 8;
        ldswo[i] = (wave * 256 + i * 64) * 8;
    }
#pragma unroll
    for (int i = 0; i < 2; i++) {
        int g = wave * 128 + i * 64 + lane;       // 0..511
        int r = g >> 3, cg = (g & 7) ^ (r & 7);
        gao[i]   = r * DM_ + cg * 8;
        ldsao[i] = (wave * 128 + i * 64) * 8;
    }
    const u16* Wp = W + (size_t)n0 * DM_;
    const u16* Ap = A + (size_t)m0 * DM_;

    floatx4 acc[2][4];
#pragma unroll
    for (int i = 0; i < 2; i++)
#pragma unroll
        for (int j = 0; j < 4; j++) acc[i][j] = (floatx4){0.f, 0.f, 0.f, 0.f};

    for (int k0 = 0; k0 < DM_; k0 += 64) {
        __syncthreads();
#pragma unroll
        for (int i = 0; i < 4; i++)
            load_lds16(Wp + k0 + gwo[i], &Ws[ldswo[i]]);
#pragma unroll
        for (int i = 0; i < 2; i++)
            load_lds16(Ap + k0 + gao[i], &As[ldsao[i]]);
        drain_vm();                               // DMA data LDS-visible
        __syncthreads();

#pragma unroll
        for (int ks = 0; ks < 2; ks++) {
            short8 af[2], bf[4];
#pragma unroll
            for (int rt = 0; rt < 2; rt++)
                af[rt] = *(const short8*)&As[sw_off(wm * 32 + rt * 16 + n16, ks * 4 + quad)];
#pragma unroll
            for (int ct = 0; ct < 4; ct++)
                bf[ct] = *(const short8*)&Ws[sw_off(wn * 64 + ct * 16 + n16, ks * 4 + quad)];
#pragma unroll
            for (int rt = 0; rt < 2; rt++)
#pragma unroll
                for (int ct = 0; ct < 4; ct++)
                    acc[rt][ct] = __builtin_amdgcn_mfma_f32_16x16x32_bf16(
                        af[rt], bf[ct], acc[rt][ct], 0, 0, 0);
        }
    }

#pragma unroll
    for (int rt = 0; rt < 2; rt++)
#pragma unroll
        for (int ct = 0; ct < 4; ct++) {
            const int col = n0 + wn * 64 + ct * 16 + n16;
#pragma unroll
            for (int r = 0; r < 4; r++) {
                const int row = m0 + wm * 32 + rt * 16 + quad * 4 + r;
                Cf[(size_t)row * DM_ + col] = acc[rt][ct][r] + resid[(size_t)row * DM_ + col];
            }
        }
}

// =====================================================================
// LayerNorm in-place on [M, DM] rows. grid: M, block: 256 (R12-proven)
// =====================================================================
__global__ __launch_bounds__(256) void ln_kernel(
    float* __restrict__ io, const float* __restrict__ g, const float* __restrict__ bb)
{
    const int row = blockIdx.x, t = threadIdx.x;
    float* p = io + (size_t)row * DM_;
    float x[3];
    float sum = 0.0f, sq = 0.0f;
#pragma unroll
    for (int i = 0; i < 3; i++) {
        x[i] = p[t + i * 256];
        sum += x[i];
        sq  = fmaf(x[i], x[i], sq);
    }
#pragma unroll
    for (int off = 32; off >= 1; off >>= 1) {
        sum += __shfl_xor(sum, off);
        sq  += __shfl_xor(sq, off);
    }
    __shared__ float s1[4], s2[4];
    if ((t & 63) == 0) { s1[t >> 6] = sum; s2[t >> 6] = sq; }
    __syncthreads();
    sum = s1[0] + s1[1] + s1[2] + s1[3];
    sq  = s2[0] + s2[1] + s2[2] + s2[3];
    const float mu  = sum * (1.0f / 768.0f);
    const float var = sq * (1.0f / 768.0f) - mu * mu;
    const float rs  = rsqrtf(var + 1e-12f);
#pragma unroll
    for (int i = 0; i < 3; i++) {
        const int c = t + i * 256;
        p[c] = (x[i] - mu) * rs * g[c] + bb[c];
    }
}

// =====================================================================
// Workspace (bf16 elem offsets; total ~55.5 MB <= proven 75.5 MB):
//   Hb [0,R)      -> O (final attn out, bf16) overlays after gemm_qkv
//   Wb [R, R+4W)
//   Qh, Kh, Vt    (R each)
// =====================================================================
extern "C" void kernel_launch(void* const* d_in, const int* in_sizes, int n_in,
                              void* d_out, int out_size, void* d_ws, size_t ws_size,
                              hipStream_t stream)
{
    const float* hidden = (const float*)d_in[0];
    const float* cosT   = (const float*)d_in[1];
    const float* sinT   = (const float*)d_in[2];
    const float* Wq     = (const float*)d_in[3];
    const float* bq     = (const float*)d_in[4];
    const float* Wk     = (const float*)d_in[5];
    const float* bk     = (const float*)d_in[6];
    const float* Wv     = (const float*)d_in[7];
    const float* bv     = (const float*)d_in[8];
    const float* Wo     = (const float*)d_in[9];
    const float* ln_g   = (const float*)d_in[10];
    const float* ln_b   = (const float*)d_in[11];
    float* out = (float*)d_out;

    u16* wsb = (u16*)d_ws;
    u16* Hb  = wsb;
    u16* Wb  = wsb + ROWELEMS;
    u16* Qh  = Wb + 4 * WELEMS;
    u16* Kh  = Qh + ROWELEMS;
    u16* Vt  = Kh + ROWELEMS;
    u16* Ob  = Hb;                        // overlays Hb (dead after gemm_qkv)
    u16* Wqb = Wb, *Wkb = Wb + WELEMS, *Wvb = Wb + 2 * WELEMS, *Wob = Wb + 3 * WELEMS;

    conv_bf16<<<dim3(1024, 5), 256, 0, stream>>>(hidden, Wq, Wk, Wv, Wo, Hb, Wb);

    gemm_qkv<<<dim3(DM_ / 128, M_ / 128, 3), 256, 0, stream>>>(
        Hb, Wqb, Wkb, Wvb, bq, bk, bv, cosT, sinT, Qh, Kh, Vt);

    flash_mfma<<<dim3(S_ / 128, B_ * H_), 256, 0, stream>>>(Qh, Kh, Vt, Ob);

    gemm_out<<<dim3(DM_ / 128, M_ / 64), 256, 0, stream>>>(Ob, Wob, hidden, out);

    ln_kernel<<<M_, 256, 0, stream>>>(out, ln_g, ln_b);
}

// Round 7
// 280.479 us; speedup vs baseline: 1.0527x; 1.0527x over previous
//
#include <hip/hip_runtime.h>
#include <math.h>

// Problem constants (NomicBertAttention): B=2, S=4096, DM=768, H=12, HD=64
#define B_   2
#define S_   4096
#define DM_  768
#define H_   12
#define HD_  64
#define M_   (B_ * S_)                 // 8192 rows
#define ROWELEMS ((size_t)M_ * DM_)    // 6291456 elems per [M,DM] buffer
#define WELEMS  ((size_t)DM_ * DM_)    // 589824 elems per weight

// net softmax scale: SCALING*SCALING = 1/64, times log2(e) so v_exp_f32 (2^x)
// computes e^(score/64) directly.  Folded into Q in the QKV-GEMM epilogue.
#define QSC (1.4426950408889634f / 64.0f)

typedef unsigned short u16;
typedef unsigned int   u32;
typedef __attribute__((ext_vector_type(8))) short  short8;   // 8 x bf16 (4 VGPR)
typedef __attribute__((ext_vector_type(4))) float  floatx4;  // MFMA accumulator
typedef __attribute__((ext_vector_type(4))) u32    uint32x4;

__device__ inline u16 f2bf(float f) {                 // RNE round
    u32 u = __builtin_bit_cast(u32, f);
    u += 0x7FFF + ((u >> 16) & 1);
    return (u16)(u >> 16);
}
__device__ inline float bf2f(u16 h) {
    return __builtin_bit_cast(float, (u32)h << 16);
}
__device__ inline u32 pk_trunc(float a, float b) {    // [bf16(b)<<16 | bf16(a)], truncate
    return __builtin_amdgcn_perm(__builtin_bit_cast(u32, b),
                                 __builtin_bit_cast(u32, a), 0x07060302);
}

// XOR-swizzled LDS offset, pitch 64 bf16 (128 B) rows:
// element (r, c) lives at r*64 + ((c/8 ^ (r&7))*8) + c%8.
__device__ inline int sw_off(int r, int cg) {         // cg = c>>3 (8-elem group)
    return (r << 6) + ((cg ^ (r & 7)) << 3);
}

// Async global->LDS 16B DMA (global_load_lds_dwordx4). LDS dest is
// wave-uniform base + lane*16; we permute the per-lane GLOBAL address so the
// content lands in the swizzled layout (same 128B lines -> still coalesced).
__device__ __forceinline__ void load_lds16(const u16* g, u16* l) {
    __builtin_amdgcn_global_load_lds(
        (const __attribute__((address_space(1))) u32*)g,
        (__attribute__((address_space(3))) u32*)l, 16, 0, 0);
}

// Explicit waitcnt encodings: simm16 = lgkmcnt<<8 | expcnt<<4 | vmcnt[3:0].
// R11 failed post-timing validation with a timing-dependent divergence; the
// DMA->barrier visibility must not depend on the compiler's barrier lowering
// emitting the vmcnt drain.  R12 proved the explicit drain; R19 uses COUNTED
// vmcnt(4) so the 4 prefetch DMAs stay in flight across raw s_barriers
// (T3/T4).  vmcnt drains oldest-first, so "wait to <=4" always means "the
// current tile's 4 DMAs (and anything older, e.g. the qf loads) are done".
__device__ __forceinline__ void drain_vm() {
    __builtin_amdgcn_s_waitcnt(0x0F70);               // vmcnt(0)
}
__device__ __forceinline__ void wait_vm4() {
    __builtin_amdgcn_s_waitcnt(0x0F74);               // vmcnt(4)
}

// =====================================================================
// fp32 -> bf16 conversion: y=0 hidden [M,DM]; y=1..4 weights [DM,DM]
// =====================================================================
__global__ __launch_bounds__(256) void conv_bf16(
    const float* __restrict__ h,  const float* __restrict__ wq,
    const float* __restrict__ wk, const float* __restrict__ wv,
    const float* __restrict__ wo, u16* __restrict__ hb, u16* __restrict__ wb)
{
    const int y = blockIdx.y;
    const float* src; u16* dst; size_t n4;
    if (y == 0)      { src = h;  dst = hb;              n4 = ROWELEMS / 4; }
    else if (y == 1) { src = wq; dst = wb;              n4 = WELEMS / 4; }
    else if (y == 2) { src = wk; dst = wb + WELEMS;     n4 = WELEMS / 4; }
    else if (y == 3) { src = wv; dst = wb + 2 * WELEMS; n4 = WELEMS / 4; }
    else             { src = wo; dst = wb + 3 * WELEMS; n4 = WELEMS / 4; }
    const size_t stride = (size_t)gridDim.x * 256;
    for (size_t i = blockIdx.x * 256 + threadIdx.x; i < n4; i += stride) {
        float4 v = *(const float4*)&src[i * 4];
        u32 p0 = (u32)f2bf(v.x) | ((u32)f2bf(v.y) << 16);
        u32 p1 = (u32)f2bf(v.z) | ((u32)f2bf(v.w) << 16);
        *(uint2*)&dst[i * 4] = make_uint2(p0, p1);
    }
}

// =====================================================================
// Fused QKV GEMM + RoPE + head-major repack.
// 128x128 tile, BK=64, 2x2 waves, 16x16x32 MFMA, global_load_lds staging
// into swizzled LDS.
// Epilogue z=0/1: rope -> PAIR-INTERLEAVED Qh/Kh rows (u32 slot hd1 holds
// the rotated pair (hd1, hd1+32)); dot products are invariant under a
// fixed permutation applied to BOTH Q and K rows, so flash is unchanged.
// Epilogue z=2: transpose -> Vt[B,H,HD,S].
// =====================================================================
__global__ __launch_bounds__(256, 3) void gemm_qkv(
    const u16* __restrict__ A,
    const u16* __restrict__ W0, const u16* __restrict__ W1, const u16* __restrict__ W2,
    const float* __restrict__ b0, const float* __restrict__ b1, const float* __restrict__ b2,
    const float* __restrict__ cosT, const float* __restrict__ sinT,
    u16* __restrict__ Qh, u16* __restrict__ Kh, u16* __restrict__ Vt)
{
    __shared__ __align__(16) u16 As[128 * 64];   // 16 KB, swizzled
    __shared__ __align__(16) u16 Ws[128 * 64];   // 16 KB, swizzled

    const int tid  = threadIdx.x;
    const int wave = tid >> 6, lane = tid & 63;
    const int n16  = lane & 15, quad = lane >> 4;
    const int wm   = wave >> 1, wn = wave & 1;
    const int m0   = blockIdx.y * 128, n0 = blockIdx.x * 128;
    const int z    = blockIdx.z;

    const u16* Wz = (z == 0) ? W0 : (z == 1) ? W1 : W2;
    const float* bz = (z == 0) ? b0 : (z == 1) ? b1 : b2;

    // staging lane constants: granule g covers (r, content-group cg = slot^(r&7))
    int gao[4], ldso[4];
#pragma unroll
    for (int i = 0; i < 4; i++) {
        int g = wave * 256 + i * 64 + lane;      // 0..1023
        int r = g >> 3, cg = (g & 7) ^ (r & 7);
        gao[i]  = r * DM_ + cg * 8;
        ldso[i] = (wave * 256 + i * 64) * 8;
    }
    const u16* Ap = A  + (size_t)m0 * DM_;
    const u16* Wp = Wz + (size_t)n0 * DM_;

    floatx4 acc[4][4];
#pragma unroll
    for (int i = 0; i < 4; i++)
#pragma unroll
        for (int j = 0; j < 4; j++) acc[i][j] = (floatx4){0.f, 0.f, 0.f, 0.f};

    for (int k0 = 0; k0 < DM_; k0 += 64) {
        __syncthreads();                          // prev tile fully read
#pragma unroll
        for (int i = 0; i < 4; i++) {
            load_lds16(Ap + k0 + gao[i], &As[ldso[i]]);
            load_lds16(Wp + k0 + gao[i], &Ws[ldso[i]]);
        }
        drain_vm();                               // DMA data LDS-visible
        __syncthreads();                          // tile landed for ALL waves
#pragma unroll
        for (int ks = 0; ks < 2; ks++) {
            short8 af[4], bf[4];
#pragma unroll
            for (int t = 0; t < 4; t++) {
                af[t] = *(const short8*)&As[sw_off(wm * 64 + t * 16 + n16, ks * 4 + quad)];
                bf[t] = *(const short8*)&Ws[sw_off(wn * 64 + t * 16 + n16, ks * 4 + quad)];
            }
#pragma unroll
            for (int i = 0; i < 4; i++)
#pragma unroll
                for (int j = 0; j < 4; j++)
                    acc[i][j] = __builtin_amdgcn_mfma_f32_16x16x32_bf16(
                        af[i], bf[j], acc[i][j], 0, 0, 0);
        }
    }

    // ---- epilogue: C/D layout col = n16, row = quad*4+r ----
    if (z == 2) {
#pragma unroll
        for (int i = 0; i < 4; i++)
#pragma unroll
            for (int j = 0; j < 4; j++) {
                const int col = n0 + wn * 64 + j * 16 + n16;
                const int h = col >> 6, hd = col & 63;
                const int row0 = m0 + wm * 64 + i * 16 + quad * 4;
                const int b = row0 >> 12, s0 = row0 & 4095;
                const float bias = bz[col];
                float v0 = acc[i][j][0] + bias, v1 = acc[i][j][1] + bias;
                float v2 = acc[i][j][2] + bias, v3 = acc[i][j][3] + bias;
                u32 w0 = (u32)f2bf(v0) | ((u32)f2bf(v1) << 16);
                u32 w1 = (u32)f2bf(v2) | ((u32)f2bf(v3) << 16);
                *(uint2*)&Vt[((size_t)(b * H_ + h) * HD_ + hd) * S_ + s0] = make_uint2(w0, w1);
            }
    } else {
        u32* Out32 = (u32*)((z == 0) ? Qh : Kh);
        const float sc_ = (z == 0) ? QSC : 1.0f;
#pragma unroll
        for (int i = 0; i < 4; i++)
#pragma unroll
            for (int j = 0; j < 2; j++) {
                const int col1 = n0 + wn * 64 + j * 16 + n16;   // hd1 < 32
                const int col2 = col1 + 32;
                const int h = col1 >> 6, hd1 = col1 & 63;       // hd1 in [0,32)
                const float bias1 = bz[col1], bias2 = bz[col2];
#pragma unroll
                for (int r = 0; r < 4; r++) {
                    const int row = m0 + wm * 64 + i * 16 + quad * 4 + r;
                    const int b = row >> 12, s = row & 4095;
                    const float c  = cosT[s * HD_ + hd1];
                    const float sn = sinT[s * HD_ + hd1];
                    const float x1 = acc[i][j][r] + bias1;
                    const float x2 = acc[i][j + 2][r] + bias2;
                    const float y1 = (x1 * c - x2 * sn) * sc_;
                    const float y2 = (x2 * c + x1 * sn) * sc_;
                    // pair-interleaved: u32 slot hd1 of the 32-u32 row
                    Out32[(((size_t)(b * H_ + h) * S_ + s) << 5) + hd1] =
                        (u32)f2bf(y1) | ((u32)f2bf(y2) << 16);
                }
            }
    }
}

// =====================================================================
// Flash attention, bf16 MFMA, static softmax.
// grid (S/128, B*H) = 768 blocks = 3/CU; 64 K-tiles/block; 4 waves,
// each wave owns 32 q-rows (rt=2) -- the R17 shape (108.8us proven).
//
// R19: STATIC DOUBLE-BUFFER + COUNTED vmcnt on R17 (post-mortem of
// R18: rt=4 halved LDS demand but its register appetite dropped
// occupancy 3->2 blocks/CU -> net loss.  R17's stall budget: 261k
// cyc/CU total vs overlap floor max(LDS 147k, MFMA 134k) -> ~114k
// cycles of staging serialization from the per-iter vmcnt(0)+barrier
// round trip).  R15's earlier pipeline attempt failed from runtime-
// `cur` addressing VALU overhead + a saturated LDS pipe; both are
// gone now: the loop is unrolled x2 over two NAMED buffer pairs
// (Ks0/Vs0, Ks1/Vs1 -- zero dynamic indexing, rule #20) and LDS is at
// 56% post-R17.  Per half-iter: stage(next -> other buf), vmcnt(4)
// (drains the current tile's 4 DMAs, leaves the 4 prefetch DMAs in
// flight ACROSS the raw s_barrier), compute, raw s_barrier.  Raw
// __builtin_amdgcn_s_barrier is required: __syncthreads' lowering
// drains vmcnt(0) and would kill the prefetch.  vmcnt drains
// oldest-first, so the invariant "tile t's DMAs done, tile t+1's in
// flight" holds even if the compiler sinks the qf loads.
//
// rho row-permutation + in-register pa packing carried from R17
// unchanged:  K staged with row shuffle rho (bits b4<-b3, b3<-b2,
// b2<-b4), so lane (n16,quad)'s S^T values ARE its PV A-fragment:
// pa[rt][ks] = {pk(sct[2ks][rt]), pk(sct[2ks+1][rt])}.  No Ps LDS.
//
// __launch_bounds__(256,3): VGPR cap 168 (R17 allocated 64; dbuf adds
// only a second set of constant LDS bases).  LDS 32 KB -> 3 blocks/CU
// (grid-limited).  DO NOT raise to (256,5): R10 -> forced spill.
// =====================================================================
__global__ __launch_bounds__(256, 3) void flash_mfma(
    const u16* __restrict__ Qh, const u16* __restrict__ Kh,
    const u16* __restrict__ Vt, u16* __restrict__ O)
{
    __shared__ __align__(16) u16 Ks0[64 * 64];    // 8 KB  K[named kcol][d], rho-permuted
    __shared__ __align__(16) u16 Vs0[64 * 64];    // 8 KB  V^T[d][kcol]
    __shared__ __align__(16) u16 Ks1[64 * 64];    // 8 KB  (double buffer)
    __shared__ __align__(16) u16 Vs1[64 * 64];    // 8 KB

    const int tid  = threadIdx.x;
    const int wave = tid >> 6, lane = tid & 63;
    const int n16  = lane & 15, quad = lane >> 4;
    const int qt   = blockIdx.x;
    const int bh   = blockIdx.y;
    const size_t qk_base = (size_t)bh * S_ * HD_;
    const size_t vt_base = (size_t)bh * HD_ * S_;
    const int q0   = qt * 128;
    const int wrow = wave * 32;

    // Q fragments in registers (A/B frag layout: lane&15 x (quad*8+j))
    short8 qf[2][2];
#pragma unroll
    for (int rt = 0; rt < 2; rt++)
#pragma unroll
        for (int ks = 0; ks < 2; ks++)
            qf[rt][ks] = *(const short8*)&Qh[qk_base +
                (size_t)(q0 + wrow + rt * 16 + n16) * HD_ + ks * 32 + quad * 8];

    short8 ones;
#pragma unroll
    for (int j = 0; j < 8; j++) ones[j] = (short)0x3F80;   // bf16 1.0

    // staging lane constants (swizzled global addresses).
    // K rows permuted by rho: LDS named row n holds physical K row rho(n).
    int gk_off[2], gv_off[2], ldso[2];
#pragma unroll
    for (int i = 0; i < 2; i++) {
        int g = wave * 128 + i * 64 + lane;       // 0..511
        int r = g >> 3, cg = (g & 7) ^ (r & 7);
        int rk = (r & 0x23) | ((r & 8) << 1) | ((r & 4) << 1) | ((r & 16) >> 2);
        gk_off[i] = rk * HD_ + cg * 8;
        gv_off[i] = r  * S_  + cg * 8;
        ldso[i]   = (wave * 128 + i * 64) * 8;
    }

    floatx4 o_acc[2][4];
    floatx4 o_l[2];                   // l accumulator (ones-MFMA, C-layout)
#pragma unroll
    for (int rt = 0; rt < 2; rt++) {
        o_l[rt] = (floatx4){0.f, 0.f, 0.f, 0.f};
#pragma unroll
        for (int dt = 0; dt < 4; dt++) o_acc[rt][dt] = (floatx4){0.f, 0.f, 0.f, 0.f};
    }

    const u16* Kg = Kh + qk_base;
    const u16* Vg = Vt + vt_base;

// stage one 64-kcol tile: 2 K DMAs + 2 V DMAs per wave (4 total)
#define STAGE(KSRC, VSRC, KDST, VDST)                                   \
    do {                                                                \
        _Pragma("unroll")                                               \
        for (int i_ = 0; i_ < 2; i_++) {                                \
            load_lds16((KSRC) + gk_off[i_], &(KDST)[ldso[i_]]);         \
            load_lds16((VSRC) + gv_off[i_], &(VDST)[ldso[i_]]);         \
        }                                                               \
    } while (0)

// R17 compute body on one tile (16 ds_read_b128, 36 MFMA, in-reg pa)
#define COMPUTE_TILE(KSB, VSB)                                          \
    do {                                                                \
        floatx4 sct[4][2];                                              \
        _Pragma("unroll")                                               \
        for (int ct = 0; ct < 4; ct++)                                  \
            _Pragma("unroll")                                           \
            for (int rt = 0; rt < 2; rt++)                              \
                sct[ct][rt] = (floatx4){0.f, 0.f, 0.f, 0.f};            \
        _Pragma("unroll")                                               \
        for (int ks = 0; ks < 2; ks++) {                                \
            short8 kf[4];                                               \
            _Pragma("unroll")                                           \
            for (int ct = 0; ct < 4; ct++)                              \
                kf[ct] = *(const short8*)&(KSB)[sw_off(ct * 16 + n16,   \
                                                       ks * 4 + quad)]; \
            _Pragma("unroll")                                           \
            for (int ct = 0; ct < 4; ct++)                              \
                _Pragma("unroll")                                       \
                for (int rt = 0; rt < 2; rt++)                          \
                    sct[ct][rt] = __builtin_amdgcn_mfma_f32_16x16x32_bf16( \
                        kf[ct], qf[rt][ks], sct[ct][rt], 0, 0, 0);      \
        }                                                               \
        short8 pa[2][2];                                                \
        _Pragma("unroll")                                               \
        for (int rt = 0; rt < 2; rt++)                                  \
            _Pragma("unroll")                                           \
            for (int ks = 0; ks < 2; ks++) {                            \
                const floatx4 lo = sct[2 * ks][rt];                     \
                const floatx4 hi = sct[2 * ks + 1][rt];                 \
                uint32x4 w;                                             \
                w[0] = pk_trunc(__builtin_amdgcn_exp2f(lo[0]),          \
                                __builtin_amdgcn_exp2f(lo[1]));         \
                w[1] = pk_trunc(__builtin_amdgcn_exp2f(lo[2]),          \
                                __builtin_amdgcn_exp2f(lo[3]));         \
                w[2] = pk_trunc(__builtin_amdgcn_exp2f(hi[0]),          \
                                __builtin_amdgcn_exp2f(hi[1]));         \
                w[3] = pk_trunc(__builtin_amdgcn_exp2f(hi[2]),          \
                                __builtin_amdgcn_exp2f(hi[3]));         \
                pa[rt][ks] = __builtin_bit_cast(short8, w);             \
            }                                                           \
        _Pragma("unroll")                                               \
        for (int ks = 0; ks < 2; ks++) {                                \
            short8 vb[4];                                               \
            _Pragma("unroll")                                           \
            for (int dt = 0; dt < 4; dt++)                              \
                vb[dt] = *(const short8*)&(VSB)[sw_off(dt * 16 + n16,   \
                                                       ks * 4 + quad)]; \
            _Pragma("unroll")                                           \
            for (int rt = 0; rt < 2; rt++) {                            \
                _Pragma("unroll")                                       \
                for (int dt = 0; dt < 4; dt++)                          \
                    o_acc[rt][dt] = __builtin_amdgcn_mfma_f32_16x16x32_bf16( \
                        pa[rt][ks], vb[dt], o_acc[rt][dt], 0, 0, 0);    \
                o_l[rt] = __builtin_amdgcn_mfma_f32_16x16x32_bf16(      \
                    pa[rt][ks], ones, o_l[rt], 0, 0, 0);                \
            }                                                           \
        }                                                               \
    } while (0)

    // ---- prologue: tile 0 -> buffer 0 ----
    STAGE(Kg, Vg, Ks0, Vs0);

    for (int kt = 0; kt < 64; kt += 2) {
        // -- half A: compute tile kt (buf0); prefetch kt+1 -> buf1 --
        STAGE(Kg + 64 * HD_, Vg + 64, Ks1, Vs1);
        wait_vm4();                               // tile kt landed; kt+1 in flight
        __builtin_amdgcn_s_barrier();             // tile kt visible to ALL waves
        COMPUTE_TILE(Ks0, Vs0);
        __builtin_amdgcn_s_barrier();             // all waves done reading buf0

        // -- half B: compute tile kt+1 (buf1); prefetch kt+2 -> buf0 --
        if (kt + 2 < 64) {
            STAGE(Kg + 2 * 64 * HD_, Vg + 2 * 64, Ks0, Vs0);
            wait_vm4();                           // tile kt+1 landed; kt+2 in flight
        } else {
            drain_vm();                           // last tile: full drain
        }
        __builtin_amdgcn_s_barrier();             // tile kt+1 visible to ALL waves
        COMPUTE_TILE(Ks1, Vs1);
        __builtin_amdgcn_s_barrier();             // all waves done reading buf1

        Kg += 2 * 64 * HD_;
        Vg += 2 * 64;
    }
#undef STAGE
#undef COMPUTE_TILE

    // ---- epilogue: normalize by complete l (C-layout: row=quad*4+r, all
    // cols equal, so every lane holds its row's l) and write final bf16 O ----
    const int b = bh / H_, h = bh % H_;
#pragma unroll
    for (int rt = 0; rt < 2; rt++)
#pragma unroll
        for (int r = 0; r < 4; r++) {
            const float inv = 1.0f / o_l[rt][r];
            const int srow = q0 + wrow + rt * 16 + quad * 4 + r;
            u16* Orow = O + ((size_t)b * S_ + srow) * DM_ + h * HD_;
#pragma unroll
            for (int dt = 0; dt < 4; dt++)
                Orow[dt * 16 + n16] = f2bf(o_acc[rt][dt][r] * inv);
        }
}

// =====================================================================
// Out-proj GEMM, pure DMA-staged (R14: flash output is pre-normalized):
//   out = A @ Wo^T + hidden (fp32).  A and W both via global_load_lds.
// Tile 64(m) x 128(n), BK=64, 2x2 waves (wave: 32 rows x 64 cols).
// =====================================================================
__global__ __launch_bounds__(256, 4) void gemm_out(
    const u16* __restrict__ A, const u16* __restrict__ W,
    const float* __restrict__ resid, float* __restrict__ Cf)
{
    __shared__ __align__(16) u16 As[64 * 64];     //  8 KB, swizzled
    __shared__ __align__(16) u16 Ws[128 * 64];    // 16 KB, swizzled

    const int tid  = threadIdx.x;
    const int wave = tid >> 6, lane = tid & 63;
    const int n16  = lane & 15, quad = lane >> 4;
    const int wm   = wave >> 1, wn = wave & 1;
    const int m0   = blockIdx.y * 64, n0 = blockIdx.x * 128;

    // W: 1024 granules (4 DMA/thread); A: 512 granules (2 DMA/thread)
    int gwo[4], ldswo[4], gao[2], ldsao[2];
#pragma unroll
    for (int i = 0; i < 4; i++) {
        int g = wave * 256 + i * 64 + lane;
        int r = g >> 3, cg = (g & 7) ^ (r & 7);
        gwo[i]   = r * DM_ + cg * 8;
        ldswo[i] = (wave * 256 + i * 64) * 8;
    }
#pragma unroll
    for (int i = 0; i < 2; i++) {
        int g = wave * 128 + i * 64 + lane;       // 0..511
        int r = g >> 3, cg = (g & 7) ^ (r & 7);
        gao[i]   = r * DM_ + cg * 8;
        ldsao[i] = (wave * 128 + i * 64) * 8;
    }
    const u16* Wp = W + (size_t)n0 * DM_;
    const u16* Ap = A + (size_t)m0 * DM_;

    floatx4 acc[2][4];
#pragma unroll
    for (int i = 0; i < 2; i++)
#pragma unroll
        for (int j = 0; j < 4; j++) acc[i][j] = (floatx4){0.f, 0.f, 0.f, 0.f};

    for (int k0 = 0; k0 < DM_; k0 += 64) {
        __syncthreads();
#pragma unroll
        for (int i = 0; i < 4; i++)
            load_lds16(Wp + k0 + gwo[i], &Ws[ldswo[i]]);
#pragma unroll
        for (int i = 0; i < 2; i++)
            load_lds16(Ap + k0 + gao[i], &As[ldsao[i]]);
        drain_vm();                               // DMA data LDS-visible
        __syncthreads();

#pragma unroll
        for (int ks = 0; ks < 2; ks++) {
            short8 af[2], bf[4];
#pragma unroll
            for (int rt = 0; rt < 2; rt++)
                af[rt] = *(const short8*)&As[sw_off(wm * 32 + rt * 16 + n16, ks * 4 + quad)];
#pragma unroll
            for (int ct = 0; ct < 4; ct++)
                bf[ct] = *(const short8*)&Ws[sw_off(wn * 64 + ct * 16 + n16, ks * 4 + quad)];
#pragma unroll
            for (int rt = 0; rt < 2; rt++)
#pragma unroll
                for (int ct = 0; ct < 4; ct++)
                    acc[rt][ct] = __builtin_amdgcn_mfma_f32_16x16x32_bf16(
                        af[rt], bf[ct], acc[rt][ct], 0, 0, 0);
        }
    }

#pragma unroll
    for (int rt = 0; rt < 2; rt++)
#pragma unroll
        for (int ct = 0; ct < 4; ct++) {
            const int col = n0 + wn * 64 + ct * 16 + n16;
#pragma unroll
            for (int r = 0; r < 4; r++) {
                const int row = m0 + wm * 32 + rt * 16 + quad * 4 + r;
                Cf[(size_t)row * DM_ + col] = acc[rt][ct][r] + resid[(size_t)row * DM_ + col];
            }
        }
}

// =====================================================================
// LayerNorm in-place on [M, DM] rows. grid: M, block: 256 (R12-proven)
// =====================================================================
__global__ __launch_bounds__(256) void ln_kernel(
    float* __restrict__ io, const float* __restrict__ g, const float* __restrict__ bb)
{
    const int row = blockIdx.x, t = threadIdx.x;
    float* p = io + (size_t)row * DM_;
    float x[3];
    float sum = 0.0f, sq = 0.0f;
#pragma unroll
    for (int i = 0; i < 3; i++) {
        x[i] = p[t + i * 256];
        sum += x[i];
        sq  = fmaf(x[i], x[i], sq);
    }
#pragma unroll
    for (int off = 32; off >= 1; off >>= 1) {
        sum += __shfl_xor(sum, off);
        sq  += __shfl_xor(sq, off);
    }
    __shared__ float s1[4], s2[4];
    if ((t & 63) == 0) { s1[t >> 6] = sum; s2[t >> 6] = sq; }
    __syncthreads();
    sum = s1[0] + s1[1] + s1[2] + s1[3];
    sq  = s2[0] + s2[1] + s2[2] + s2[3];
    const float mu  = sum * (1.0f / 768.0f);
    const float var = sq * (1.0f / 768.0f) - mu * mu;
    const float rs  = rsqrtf(var + 1e-12f);
#pragma unroll
    for (int i = 0; i < 3; i++) {
        const int c = t + i * 256;
        p[c] = (x[i] - mu) * rs * g[c] + bb[c];
    }
}

// =====================================================================
// Workspace (bf16 elem offsets; total ~55.5 MB <= proven 75.5 MB):
//   Hb [0,R)      -> O (final attn out, bf16) overlays after gemm_qkv
//   Wb [R, R+4W)
//   Qh, Kh, Vt    (R each)
// =====================================================================
extern "C" void kernel_launch(void* const* d_in, const int* in_sizes, int n_in,
                              void* d_out, int out_size, void* d_ws, size_t ws_size,
                              hipStream_t stream)
{
    const float* hidden = (const float*)d_in[0];
    const float* cosT   = (const float*)d_in[1];
    const float* sinT   = (const float*)d_in[2];
    const float* Wq     = (const float*)d_in[3];
    const float* bq     = (const float*)d_in[4];
    const float* Wk     = (const float*)d_in[5];
    const float* bk     = (const float*)d_in[6];
    const float* Wv     = (const float*)d_in[7];
    const float* bv     = (const float*)d_in[8];
    const float* Wo     = (const float*)d_in[9];
    const float* ln_g   = (const float*)d_in[10];
    const float* ln_b   = (const float*)d_in[11];
    float* out = (float*)d_out;

    u16* wsb = (u16*)d_ws;
    u16* Hb  = wsb;
    u16* Wb  = wsb + ROWELEMS;
    u16* Qh  = Wb + 4 * WELEMS;
    u16* Kh  = Qh + ROWELEMS;
    u16* Vt  = Kh + ROWELEMS;
    u16* Ob  = Hb;                        // overlays Hb (dead after gemm_qkv)
    u16* Wqb = Wb, *Wkb = Wb + WELEMS, *Wvb = Wb + 2 * WELEMS, *Wob = Wb + 3 * WELEMS;

    conv_bf16<<<dim3(1024, 5), 256, 0, stream>>>(hidden, Wq, Wk, Wv, Wo, Hb, Wb);

    gemm_qkv<<<dim3(DM_ / 128, M_ / 128, 3), 256, 0, stream>>>(
        Hb, Wqb, Wkb, Wvb, bq, bk, bv, cosT, sinT, Qh, Kh, Vt);

    flash_mfma<<<dim3(S_ / 128, B_ * H_), 256, 0, stream>>>(Qh, Kh, Vt, Ob);

    gemm_out<<<dim3(DM_ / 128, M_ / 64), 256, 0, stream>>>(Ob, Wob, hidden, out);

    ln_kernel<<<M_, 256, 0, stream>>>(out, ln_g, ln_b);
}

// Round 8
// 271.870 us; speedup vs baseline: 1.0860x; 1.0317x over previous
//
#include <hip/hip_runtime.h>
#include <math.h>

// Problem constants (NomicBertAttention): B=2, S=4096, DM=768, H=12, HD=64
#define B_   2
#define S_   4096
#define DM_  768
#define H_   12
#define HD_  64
#define M_   (B_ * S_)                 // 8192 rows
#define ROWELEMS ((size_t)M_ * DM_)    // 6291456 elems per [M,DM] buffer
#define WELEMS  ((size_t)DM_ * DM_)    // 589824 elems per weight

// net softmax scale: SCALING*SCALING = 1/64, times log2(e) so v_exp_f32 (2^x)
// computes e^(score/64) directly.  Folded into Q in the QKV-GEMM epilogue.
#define QSC (1.4426950408889634f / 64.0f)

typedef unsigned short u16;
typedef unsigned int   u32;
typedef __attribute__((ext_vector_type(8))) short  short8;   // 8 x bf16 (4 VGPR)
typedef __attribute__((ext_vector_type(4))) float  floatx4;  // MFMA accumulator
typedef __attribute__((ext_vector_type(4))) u32    uint32x4;

__device__ inline u16 f2bf(float f) {                 // RNE round
    u32 u = __builtin_bit_cast(u32, f);
    u += 0x7FFF + ((u >> 16) & 1);
    return (u16)(u >> 16);
}
__device__ inline float bf2f(u16 h) {
    return __builtin_bit_cast(float, (u32)h << 16);
}
__device__ inline u32 pk_trunc(float a, float b) {    // [bf16(b)<<16 | bf16(a)], truncate
    return __builtin_amdgcn_perm(__builtin_bit_cast(u32, b),
                                 __builtin_bit_cast(u32, a), 0x07060302);
}

// XOR-swizzled LDS offset, pitch 64 bf16 (128 B) rows:
// element (r, c) lives at r*64 + ((c/8 ^ (r&7))*8) + c%8.
__device__ inline int sw_off(int r, int cg) {         // cg = c>>3 (8-elem group)
    return (r << 6) + ((cg ^ (r & 7)) << 3);
}

// Async global->LDS 16B DMA (global_load_lds_dwordx4). LDS dest is
// wave-uniform base + lane*16; we permute the per-lane GLOBAL address so the
// content lands in the swizzled layout (same 128B lines -> still coalesced).
__device__ __forceinline__ void load_lds16(const u16* g, u16* l) {
    __builtin_amdgcn_global_load_lds(
        (const __attribute__((address_space(1))) u32*)g,
        (__attribute__((address_space(3))) u32*)l, 16, 0, 0);
}

// Explicit waitcnt encodings: simm16 = lgkmcnt<<8 | expcnt<<4 | vmcnt[3:0].
// R11 failed post-timing validation with a timing-dependent divergence; the
// DMA->barrier visibility must not depend on the compiler's barrier lowering
// emitting the vmcnt drain.  R12 proved the explicit drain; R19 validated
// COUNTED vmcnt(4) across raw s_barriers on HW (passed, absmax unchanged).
// vmcnt drains oldest-first: "wait to <=4" always means "the current tile's
// 4 DMAs (and anything older, e.g. the qf loads) are done".
__device__ __forceinline__ void drain_vm() {
    __builtin_amdgcn_s_waitcnt(0x0F70);               // vmcnt(0)
}
__device__ __forceinline__ void wait_vm4() {
    __builtin_amdgcn_s_waitcnt(0x0F74);               // vmcnt(4)
}

// =====================================================================
// fp32 -> bf16 conversion: y=0 hidden [M,DM]; y=1..4 weights [DM,DM]
// =====================================================================
__global__ __launch_bounds__(256) void conv_bf16(
    const float* __restrict__ h,  const float* __restrict__ wq,
    const float* __restrict__ wk, const float* __restrict__ wv,
    const float* __restrict__ wo, u16* __restrict__ hb, u16* __restrict__ wb)
{
    const int y = blockIdx.y;
    const float* src; u16* dst; size_t n4;
    if (y == 0)      { src = h;  dst = hb;              n4 = ROWELEMS / 4; }
    else if (y == 1) { src = wq; dst = wb;              n4 = WELEMS / 4; }
    else if (y == 2) { src = wk; dst = wb + WELEMS;     n4 = WELEMS / 4; }
    else if (y == 3) { src = wv; dst = wb + 2 * WELEMS; n4 = WELEMS / 4; }
    else             { src = wo; dst = wb + 3 * WELEMS; n4 = WELEMS / 4; }
    const size_t stride = (size_t)gridDim.x * 256;
    for (size_t i = blockIdx.x * 256 + threadIdx.x; i < n4; i += stride) {
        float4 v = *(const float4*)&src[i * 4];
        u32 p0 = (u32)f2bf(v.x) | ((u32)f2bf(v.y) << 16);
        u32 p1 = (u32)f2bf(v.z) | ((u32)f2bf(v.w) << 16);
        *(uint2*)&dst[i * 4] = make_uint2(p0, p1);
    }
}

// =====================================================================
// Fused QKV GEMM + RoPE + head-major repack.
// 128x128 tile, BK=64, 2x2 waves, 16x16x32 MFMA, global_load_lds staging
// into swizzled LDS.
// Epilogue z=0/1: rope -> PAIR-INTERLEAVED Qh/Kh rows (u32 slot hd1 holds
// the rotated pair (hd1, hd1+32)); dot products are invariant under a
// fixed permutation applied to BOTH Q and K rows, so flash is unchanged.
// Epilogue z=2: transpose -> Vt[B,H,HD,S].
// =====================================================================
__global__ __launch_bounds__(256, 3) void gemm_qkv(
    const u16* __restrict__ A,
    const u16* __restrict__ W0, const u16* __restrict__ W1, const u16* __restrict__ W2,
    const float* __restrict__ b0, const float* __restrict__ b1, const float* __restrict__ b2,
    const float* __restrict__ cosT, const float* __restrict__ sinT,
    u16* __restrict__ Qh, u16* __restrict__ Kh, u16* __restrict__ Vt)
{
    __shared__ __align__(16) u16 As[128 * 64];   // 16 KB, swizzled
    __shared__ __align__(16) u16 Ws[128 * 64];   // 16 KB, swizzled

    const int tid  = threadIdx.x;
    const int wave = tid >> 6, lane = tid & 63;
    const int n16  = lane & 15, quad = lane >> 4;
    const int wm   = wave >> 1, wn = wave & 1;
    const int m0   = blockIdx.y * 128, n0 = blockIdx.x * 128;
    const int z    = blockIdx.z;

    const u16* Wz = (z == 0) ? W0 : (z == 1) ? W1 : W2;
    const float* bz = (z == 0) ? b0 : (z == 1) ? b1 : b2;

    // staging lane constants: granule g covers (r, content-group cg = slot^(r&7))
    int gao[4], ldso[4];
#pragma unroll
    for (int i = 0; i < 4; i++) {
        int g = wave * 256 + i * 64 + lane;      // 0..1023
        int r = g >> 3, cg = (g & 7) ^ (r & 7);
        gao[i]  = r * DM_ + cg * 8;
        ldso[i] = (wave * 256 + i * 64) * 8;
    }
    const u16* Ap = A  + (size_t)m0 * DM_;
    const u16* Wp = Wz + (size_t)n0 * DM_;

    floatx4 acc[4][4];
#pragma unroll
    for (int i = 0; i < 4; i++)
#pragma unroll
        for (int j = 0; j < 4; j++) acc[i][j] = (floatx4){0.f, 0.f, 0.f, 0.f};

    for (int k0 = 0; k0 < DM_; k0 += 64) {
        __syncthreads();                          // prev tile fully read
#pragma unroll
        for (int i = 0; i < 4; i++) {
            load_lds16(Ap + k0 + gao[i], &As[ldso[i]]);
            load_lds16(Wp + k0 + gao[i], &Ws[ldso[i]]);
        }
        drain_vm();                               // DMA data LDS-visible
        __syncthreads();                          // tile landed for ALL waves
#pragma unroll
        for (int ks = 0; ks < 2; ks++) {
            short8 af[4], bf[4];
#pragma unroll
            for (int t = 0; t < 4; t++) {
                af[t] = *(const short8*)&As[sw_off(wm * 64 + t * 16 + n16, ks * 4 + quad)];
                bf[t] = *(const short8*)&Ws[sw_off(wn * 64 + t * 16 + n16, ks * 4 + quad)];
            }
#pragma unroll
            for (int i = 0; i < 4; i++)
#pragma unroll
                for (int j = 0; j < 4; j++)
                    acc[i][j] = __builtin_amdgcn_mfma_f32_16x16x32_bf16(
                        af[i], bf[j], acc[i][j], 0, 0, 0);
        }
    }

    // ---- epilogue: C/D layout col = n16, row = quad*4+r ----
    if (z == 2) {
#pragma unroll
        for (int i = 0; i < 4; i++)
#pragma unroll
            for (int j = 0; j < 4; j++) {
                const int col = n0 + wn * 64 + j * 16 + n16;
                const int h = col >> 6, hd = col & 63;
                const int row0 = m0 + wm * 64 + i * 16 + quad * 4;
                const int b = row0 >> 12, s0 = row0 & 4095;
                const float bias = bz[col];
                float v0 = acc[i][j][0] + bias, v1 = acc[i][j][1] + bias;
                float v2 = acc[i][j][2] + bias, v3 = acc[i][j][3] + bias;
                u32 w0 = (u32)f2bf(v0) | ((u32)f2bf(v1) << 16);
                u32 w1 = (u32)f2bf(v2) | ((u32)f2bf(v3) << 16);
                *(uint2*)&Vt[((size_t)(b * H_ + h) * HD_ + hd) * S_ + s0] = make_uint2(w0, w1);
            }
    } else {
        u32* Out32 = (u32*)((z == 0) ? Qh : Kh);
        const float sc_ = (z == 0) ? QSC : 1.0f;
#pragma unroll
        for (int i = 0; i < 4; i++)
#pragma unroll
            for (int j = 0; j < 2; j++) {
                const int col1 = n0 + wn * 64 + j * 16 + n16;   // hd1 < 32
                const int col2 = col1 + 32;
                const int h = col1 >> 6, hd1 = col1 & 63;       // hd1 in [0,32)
                const float bias1 = bz[col1], bias2 = bz[col2];
#pragma unroll
                for (int r = 0; r < 4; r++) {
                    const int row = m0 + wm * 64 + i * 16 + quad * 4 + r;
                    const int b = row >> 12, s = row & 4095;
                    const float c  = cosT[s * HD_ + hd1];
                    const float sn = sinT[s * HD_ + hd1];
                    const float x1 = acc[i][j][r] + bias1;
                    const float x2 = acc[i][j + 2][r] + bias2;
                    const float y1 = (x1 * c - x2 * sn) * sc_;
                    const float y2 = (x2 * c + x1 * sn) * sc_;
                    // pair-interleaved: u32 slot hd1 of the 32-u32 row
                    Out32[(((size_t)(b * H_ + h) * S_ + s) << 5) + hd1] =
                        (u32)f2bf(y1) | ((u32)f2bf(y2) << 16);
                }
            }
    }
}

// =====================================================================
// Flash attention, bf16 MFMA, static softmax.
// grid (S/128, B*H) = 768 blocks = 3/CU; 64 K-tiles/block; 4 waves,
// each wave owns 32 q-rows (rt=2) -- the R17 shape.
//
// R20: SINGLE BARRIER PER TILE via TRIPLE BUFFER (post-mortem of R19:
// counted-vmcnt dbuf was correct but only +2% -> the stall is not DMA
// latency; it's barrier COUPLING.  Each block's 4 waves sit on 4
// different SIMDs and sync 128x/kernel; one slow SIMD idles the other
// three.  No pipe is saturated: per CU-round LDS 57%, MFMA ~50%,
// VALU ~48%).  With 3 buffers the visibility barrier for tile t ALSO
// certifies all waves finished compute(t-1), so staging tile t+2 into
// buf[(t+2)%3] (= t-1's buffer) right AFTER that barrier is race-free
// and the trailing protection barrier is deleted: 64 sync points, and
// waves may drift a full tile apart, filling LDS-pipe gaps.
// Per tile: vmcnt(4) [tile t landed, t+1 in flight] -> s_barrier ->
// STAGE(t+2) -> COMPUTE(t).  Buffer names are STATIC (loop unrolled
// x3 over named pairs -- rule #20; outer `for g` stays rolled so code
// size is one 3-phase body).  R19's pass HW-validated counted-vmcnt
// across raw barriers.  All waitcnts explicit (R11/R12 discipline).
//
// rho row-permutation + in-register pa packing carried from R17
// unchanged:  K staged with row shuffle rho (bits b4<-b3, b3<-b2,
// b2<-b4), so lane (n16,quad)'s S^T values ARE its PV A-fragment:
// pa[rt][ks] = {pk(sct[2ks][rt]), pk(sct[2ks+1][rt])}.  No Ps LDS.
//
// __launch_bounds__(256,3): VGPR cap 168 (R19 allocated 72).  LDS
// 48 KB -> 3 blocks/CU (144 KB), same as R19 (grid-limited anyway).
// DO NOT raise to (256,5): R10 -> forced spill disaster.
// =====================================================================
__global__ __launch_bounds__(256, 3) void flash_mfma(
    const u16* __restrict__ Qh, const u16* __restrict__ Kh,
    const u16* __restrict__ Vt, u16* __restrict__ O)
{
    __shared__ __align__(16) u16 Ks0[64 * 64];    // 8 KB  K[named kcol][d], rho-permuted
    __shared__ __align__(16) u16 Vs0[64 * 64];    // 8 KB  V^T[d][kcol]
    __shared__ __align__(16) u16 Ks1[64 * 64];    // 8 KB  (triple buffer)
    __shared__ __align__(16) u16 Vs1[64 * 64];    // 8 KB
    __shared__ __align__(16) u16 Ks2[64 * 64];    // 8 KB
    __shared__ __align__(16) u16 Vs2[64 * 64];    // 8 KB

    const int tid  = threadIdx.x;
    const int wave = tid >> 6, lane = tid & 63;
    const int n16  = lane & 15, quad = lane >> 4;
    const int qt   = blockIdx.x;
    const int bh   = blockIdx.y;
    const size_t qk_base = (size_t)bh * S_ * HD_;
    const size_t vt_base = (size_t)bh * HD_ * S_;
    const int q0   = qt * 128;
    const int wrow = wave * 32;

    // Q fragments in registers (A/B frag layout: lane&15 x (quad*8+j))
    short8 qf[2][2];
#pragma unroll
    for (int rt = 0; rt < 2; rt++)
#pragma unroll
        for (int ks = 0; ks < 2; ks++)
            qf[rt][ks] = *(const short8*)&Qh[qk_base +
                (size_t)(q0 + wrow + rt * 16 + n16) * HD_ + ks * 32 + quad * 8];

    short8 ones;
#pragma unroll
    for (int j = 0; j < 8; j++) ones[j] = (short)0x3F80;   // bf16 1.0

    // staging lane constants (swizzled global addresses).
    // K rows permuted by rho: LDS named row n holds physical K row rho(n).
    int gk_off[2], gv_off[2], ldso[2];
#pragma unroll
    for (int i = 0; i < 2; i++) {
        int g = wave * 128 + i * 64 + lane;       // 0..511
        int r = g >> 3, cg = (g & 7) ^ (r & 7);
        int rk = (r & 0x23) | ((r & 8) << 1) | ((r & 4) << 1) | ((r & 16) >> 2);
        gk_off[i] = rk * HD_ + cg * 8;
        gv_off[i] = r  * S_  + cg * 8;
        ldso[i]   = (wave * 128 + i * 64) * 8;
    }

    floatx4 o_acc[2][4];
    floatx4 o_l[2];                   // l accumulator (ones-MFMA, C-layout)
#pragma unroll
    for (int rt = 0; rt < 2; rt++) {
        o_l[rt] = (floatx4){0.f, 0.f, 0.f, 0.f};
#pragma unroll
        for (int dt = 0; dt < 4; dt++) o_acc[rt][dt] = (floatx4){0.f, 0.f, 0.f, 0.f};
    }

    const u16* Kg = Kh + qk_base;
    const u16* Vg = Vt + vt_base;
#define KT (64 * HD_)

// stage one 64-kcol tile: 2 K DMAs + 2 V DMAs per wave (4 total)
#define STAGE(KSRC, VSRC, KDST, VDST)                                   \
    do {                                                                \
        _Pragma("unroll")                                               \
        for (int i_ = 0; i_ < 2; i_++) {                                \
            load_lds16((KSRC) + gk_off[i_], &(KDST)[ldso[i_]]);         \
            load_lds16((VSRC) + gv_off[i_], &(VDST)[ldso[i_]]);         \
        }                                                               \
    } while (0)

// R17 compute body on one tile (16 ds_read_b128, 36 MFMA, in-reg pa)
#define COMPUTE_TILE(KSB, VSB)                                          \
    do {                                                                \
        floatx4 sct[4][2];                                              \
        _Pragma("unroll")                                               \
        for (int ct = 0; ct < 4; ct++)                                  \
            _Pragma("unroll")                                           \
            for (int rt = 0; rt < 2; rt++)                              \
                sct[ct][rt] = (floatx4){0.f, 0.f, 0.f, 0.f};            \
        _Pragma("unroll")                                               \
        for (int ks = 0; ks < 2; ks++) {                                \
            short8 kf[4];                                               \
            _Pragma("unroll")                                           \
            for (int ct = 0; ct < 4; ct++)                              \
                kf[ct] = *(const short8*)&(KSB)[sw_off(ct * 16 + n16,   \
                                                       ks * 4 + quad)]; \
            _Pragma("unroll")                                           \
            for (int ct = 0; ct < 4; ct++)                              \
                _Pragma("unroll")                                       \
                for (int rt = 0; rt < 2; rt++)                          \
                    sct[ct][rt] = __builtin_amdgcn_mfma_f32_16x16x32_bf16( \
                        kf[ct], qf[rt][ks], sct[ct][rt], 0, 0, 0);      \
        }                                                               \
        short8 pa[2][2];                                                \
        _Pragma("unroll")                                               \
        for (int rt = 0; rt < 2; rt++)                                  \
            _Pragma("unroll")                                           \
            for (int ks = 0; ks < 2; ks++) {                            \
                const floatx4 lo = sct[2 * ks][rt];                     \
                const floatx4 hi = sct[2 * ks + 1][rt];                 \
                uint32x4 w;                                             \
                w[0] = pk_trunc(__builtin_amdgcn_exp2f(lo[0]),          \
                                __builtin_amdgcn_exp2f(lo[1]));         \
                w[1] = pk_trunc(__builtin_amdgcn_exp2f(lo[2]),          \
                                __builtin_amdgcn_exp2f(lo[3]));         \
                w[2] = pk_trunc(__builtin_amdgcn_exp2f(hi[0]),          \
                                __builtin_amdgcn_exp2f(hi[1]));         \
                w[3] = pk_trunc(__builtin_amdgcn_exp2f(hi[2]),          \
                                __builtin_amdgcn_exp2f(hi[3]));         \
                pa[rt][ks] = __builtin_bit_cast(short8, w);             \
            }                                                           \
        _Pragma("unroll")                                               \
        for (int ks = 0; ks < 2; ks++) {                                \
            short8 vb[4];                                               \
            _Pragma("unroll")                                           \
            for (int dt = 0; dt < 4; dt++)                              \
                vb[dt] = *(const short8*)&(VSB)[sw_off(dt * 16 + n16,   \
                                                       ks * 4 + quad)]; \
            _Pragma("unroll")                                           \
            for (int rt = 0; rt < 2; rt++) {                            \
                _Pragma("unroll")                                       \
                for (int dt = 0; dt < 4; dt++)                          \
                    o_acc[rt][dt] = __builtin_amdgcn_mfma_f32_16x16x32_bf16( \
                        pa[rt][ks], vb[dt], o_acc[rt][dt], 0, 0, 0);    \
                o_l[rt] = __builtin_amdgcn_mfma_f32_16x16x32_bf16(      \
                    pa[rt][ks], ones, o_l[rt], 0, 0, 0);                \
            }                                                           \
        }                                                               \
    } while (0)

    // ---- prologue: tiles 0,1 -> buffers 0,1 ----
    STAGE(Kg,      Vg,      Ks0, Vs0);
    STAGE(Kg + KT, Vg + 64, Ks1, Vs1);

    // t = 3g+p computes buf p%3 and stages t+2 -> buf (t+2)%3.
    // 21 groups cover t = 0..62; tile 63 handled in the epilogue iter.
    for (int g = 0; g < 21; ++g) {
        // -- t = 3g: compute b0, stage t+2 -> b2 --
        wait_vm4();                               // tile t landed; t+1 in flight
        __builtin_amdgcn_s_barrier();             // t visible; compute(t-1) done by ALL
        STAGE(Kg + 2 * KT, Vg + 2 * 64, Ks2, Vs2);
        COMPUTE_TILE(Ks0, Vs0);
        Kg += KT; Vg += 64;

        // -- t = 3g+1: compute b1, stage t+2 -> b0 --
        wait_vm4();
        __builtin_amdgcn_s_barrier();
        STAGE(Kg + 2 * KT, Vg + 2 * 64, Ks0, Vs0);
        COMPUTE_TILE(Ks1, Vs1);
        Kg += KT; Vg += 64;

        // -- t = 3g+2: compute b2, stage t+2 -> b1 (except t=62: t+2=64) --
        wait_vm4();
        __builtin_amdgcn_s_barrier();
        if (g < 20)
            STAGE(Kg + 2 * KT, Vg + 2 * 64, Ks1, Vs1);
        COMPUTE_TILE(Ks2, Vs2);
        Kg += KT; Vg += 64;
    }
    // -- t = 63: compute b0 (staged at t=61) --
    drain_vm();                                   // last tile fully landed
    __builtin_amdgcn_s_barrier();
    COMPUTE_TILE(Ks0, Vs0);
#undef STAGE
#undef COMPUTE_TILE
#undef KT

    // ---- epilogue: normalize by complete l (C-layout: row=quad*4+r, all
    // cols equal, so every lane holds its row's l) and write final bf16 O ----
    const int b = bh / H_, h = bh % H_;
#pragma unroll
    for (int rt = 0; rt < 2; rt++)
#pragma unroll
        for (int r = 0; r < 4; r++) {
            const float inv = 1.0f / o_l[rt][r];
            const int srow = q0 + wrow + rt * 16 + quad * 4 + r;
            u16* Orow = O + ((size_t)b * S_ + srow) * DM_ + h * HD_;
#pragma unroll
            for (int dt = 0; dt < 4; dt++)
                Orow[dt * 16 + n16] = f2bf(o_acc[rt][dt][r] * inv);
        }
}

// =====================================================================
// Out-proj GEMM, pure DMA-staged (R14: flash output is pre-normalized):
//   out = A @ Wo^T + hidden (fp32).  A and W both via global_load_lds.
// Tile 64(m) x 128(n), BK=64, 2x2 waves (wave: 32 rows x 64 cols).
// =====================================================================
__global__ __launch_bounds__(256, 4) void gemm_out(
    const u16* __restrict__ A, const u16* __restrict__ W,
    const float* __restrict__ resid, float* __restrict__ Cf)
{
    __shared__ __align__(16) u16 As[64 * 64];     //  8 KB, swizzled
    __shared__ __align__(16) u16 Ws[128 * 64];    // 16 KB, swizzled

    const int tid  = threadIdx.x;
    const int wave = tid >> 6, lane = tid & 63;
    const int n16  = lane & 15, quad = lane >> 4;
    const int wm   = wave >> 1, wn = wave & 1;
    const int m0   = blockIdx.y * 64, n0 = blockIdx.x * 128;

    // W: 1024 granules (4 DMA/thread); A: 512 granules (2 DMA/thread)
    int gwo[4], ldswo[4], gao[2], ldsao[2];
#pragma unroll
    for (int i = 0; i < 4; i++) {
        int g = wave * 256 + i * 64 + lane;
        int r = g >> 3, cg = (g & 7) ^ (r & 7);
        gwo[i]   = r * DM_ + cg * 8;
        ldswo[i] = (wave * 256 + i * 64) * 8;
    }
#pragma unroll
    for (int i = 0; i < 2; i++) {
        int g = wave * 128 + i * 64 + lane;       // 0..511
        int r = g >> 3, cg = (g & 7) ^ (r & 7);
        gao[i]   = r * DM_ + cg * 8;
        ldsao[i] = (wave * 128 + i * 64) * 8;
    }
    const u16* Wp = W + (size_t)n0 * DM_;
    const u16* Ap = A + (size_t)m0 * DM_;

    floatx4 acc[2][4];
#pragma unroll
    for (int i = 0; i < 2; i++)
#pragma unroll
        for (int j = 0; j < 4; j++) acc[i][j] = (floatx4){0.f, 0.f, 0.f, 0.f};

    for (int k0 = 0; k0 < DM_; k0 += 64) {
        __syncthreads();
#pragma unroll
        for (int i = 0; i < 4; i++)
            load_lds16(Wp + k0 + gwo[i], &Ws[ldswo[i]]);
#pragma unroll
        for (int i = 0; i < 2; i++)
            load_lds16(Ap + k0 + gao[i], &As[ldsao[i]]);
        drain_vm();                               // DMA data LDS-visible
        __syncthreads();

#pragma unroll
        for (int ks = 0; ks < 2; ks++) {
            short8 af[2], bf[4];
#pragma unroll
            for (int rt = 0; rt < 2; rt++)
                af[rt] = *(const short8*)&As[sw_off(wm * 32 + rt * 16 + n16, ks * 4 + quad)];
#pragma unroll
            for (int ct = 0; ct < 4; ct++)
                bf[ct] = *(const short8*)&Ws[sw_off(wn * 64 + ct * 16 + n16, ks * 4 + quad)];
#pragma unroll
            for (int rt = 0; rt < 2; rt++)
#pragma unroll
                for (int ct = 0; ct < 4; ct++)
                    acc[rt][ct] = __builtin_amdgcn_mfma_f32_16x16x32_bf16(
                        af[rt], bf[ct], acc[rt][ct], 0, 0, 0);
        }
    }

#pragma unroll
    for (int rt = 0; rt < 2; rt++)
#pragma unroll
        for (int ct = 0; ct < 4; ct++) {
            const int col = n0 + wn * 64 + ct * 16 + n16;
#pragma unroll
            for (int r = 0; r < 4; r++) {
                const int row = m0 + wm * 32 + rt * 16 + quad * 4 + r;
                Cf[(size_t)row * DM_ + col] = acc[rt][ct][r] + resid[(size_t)row * DM_ + col];
            }
        }
}

// =====================================================================
// LayerNorm in-place on [M, DM] rows. grid: M, block: 256 (R12-proven)
// =====================================================================
__global__ __launch_bounds__(256) void ln_kernel(
    float* __restrict__ io, const float* __restrict__ g, const float* __restrict__ bb)
{
    const int row = blockIdx.x, t = threadIdx.x;
    float* p = io + (size_t)row * DM_;
    float x[3];
    float sum = 0.0f, sq = 0.0f;
#pragma unroll
    for (int i = 0; i < 3; i++) {
        x[i] = p[t + i * 256];
        sum += x[i];
        sq  = fmaf(x[i], x[i], sq);
    }
#pragma unroll
    for (int off = 32; off >= 1; off >>= 1) {
        sum += __shfl_xor(sum, off);
        sq  += __shfl_xor(sq, off);
    }
    __shared__ float s1[4], s2[4];
    if ((t & 63) == 0) { s1[t >> 6] = sum; s2[t >> 6] = sq; }
    __syncthreads();
    sum = s1[0] + s1[1] + s1[2] + s1[3];
    sq  = s2[0] + s2[1] + s2[2] + s2[3];
    const float mu  = sum * (1.0f / 768.0f);
    const float var = sq * (1.0f / 768.0f) - mu * mu;
    const float rs  = rsqrtf(var + 1e-12f);
#pragma unroll
    for (int i = 0; i < 3; i++) {
        const int c = t + i * 256;
        p[c] = (x[i] - mu) * rs * g[c] + bb[c];
    }
}

// =====================================================================
// Workspace (bf16 elem offsets; total ~55.5 MB <= proven 75.5 MB):
//   Hb [0,R)      -> O (final attn out, bf16) overlays after gemm_qkv
//   Wb [R, R+4W)
//   Qh, Kh, Vt    (R each)
// =====================================================================
extern "C" void kernel_launch(void* const* d_in, const int* in_sizes, int n_in,
                              void* d_out, int out_size, void* d_ws, size_t ws_size,
                              hipStream_t stream)
{
    const float* hidden = (const float*)d_in[0];
    const float* cosT   = (const float*)d_in[1];
    const float* sinT   = (const float*)d_in[2];
    const float* Wq     = (const float*)d_in[3];
    const float* bq     = (const float*)d_in[4];
    const float* Wk     = (const float*)d_in[5];
    const float* bk     = (const float*)d_in[6];
    const float* Wv     = (const float*)d_in[7];
    const float* bv     = (const float*)d_in[8];
    const float* Wo     = (const float*)d_in[9];
    const float* ln_g   = (const float*)d_in[10];
    const float* ln_b   = (const float*)d_in[11];
    float* out = (float*)d_out;

    u16* wsb = (u16*)d_ws;
    u16* Hb  = wsb;
    u16* Wb  = wsb + ROWELEMS;
    u16* Qh  = Wb + 4 * WELEMS;
    u16* Kh  = Qh + ROWELEMS;
    u16* Vt  = Kh + ROWELEMS;
    u16* Ob  = Hb;                        // overlays Hb (dead after gemm_qkv)
    u16* Wqb = Wb, *Wkb = Wb + WELEMS, *Wvb = Wb + 2 * WELEMS, *Wob = Wb + 3 * WELEMS;

    conv_bf16<<<dim3(1024, 5), 256, 0, stream>>>(hidden, Wq, Wk, Wv, Wo, Hb, Wb);

    gemm_qkv<<<dim3(DM_ / 128, M_ / 128, 3), 256, 0, stream>>>(
        Hb, Wqb, Wkb, Wvb, bq, bk, bv, cosT, sinT, Qh, Kh, Vt);

    flash_mfma<<<dim3(S_ / 128, B_ * H_), 256, 0, stream>>>(Qh, Kh, Vt, Ob);

    gemm_out<<<dim3(DM_ / 128, M_ / 64), 256, 0, stream>>>(Ob, Wob, hidden, out);

    ln_kernel<<<M_, 256, 0, stream>>>(out, ln_g, ln_b);
}

// Round 9
// 271.303 us; speedup vs baseline: 1.0883x; 1.0021x over previous
//
#include <hip/hip_runtime.h>
#include <math.h>

// Problem constants (NomicBertAttention): B=2, S=4096, DM=768, H=12, HD=64
#define B_   2
#define S_   4096
#define DM_  768
#define H_   12
#define HD_  64
#define M_   (B_ * S_)                 // 8192 rows
#define ROWELEMS ((size_t)M_ * DM_)    // 6291456 elems per [M,DM] buffer
#define WELEMS  ((size_t)DM_ * DM_)    // 589824 elems per weight

// net softmax scale: SCALING*SCALING = 1/64, times log2(e) so v_exp_f32 (2^x)
// computes e^(score/64) directly.  Folded into Q in the QKV-GEMM epilogue.
#define QSC (1.4426950408889634f / 64.0f)

typedef unsigned short u16;
typedef unsigned int   u32;
typedef __attribute__((ext_vector_type(8))) short  short8;   // 8 x bf16 (4 VGPR)
typedef __attribute__((ext_vector_type(4))) float  floatx4;  // MFMA accumulator
typedef __attribute__((ext_vector_type(4))) u32    uint32x4;

__device__ inline u16 f2bf(float f) {                 // RNE round
    u32 u = __builtin_bit_cast(u32, f);
    u += 0x7FFF + ((u >> 16) & 1);
    return (u16)(u >> 16);
}
__device__ inline float bf2f(u16 h) {
    return __builtin_bit_cast(float, (u32)h << 16);
}
__device__ inline u32 pk_trunc(float a, float b) {    // [bf16(b)<<16 | bf16(a)], truncate
    return __builtin_amdgcn_perm(__builtin_bit_cast(u32, b),
                                 __builtin_bit_cast(u32, a), 0x07060302);
}

// XOR-swizzled LDS offset, pitch 64 bf16 (128 B) rows:
// element (r, c) lives at r*64 + ((c/8 ^ (r&7))*8) + c%8.
__device__ inline int sw_off(int r, int cg) {         // cg = c>>3 (8-elem group)
    return (r << 6) + ((cg ^ (r & 7)) << 3);
}

// Async global->LDS 16B DMA (global_load_lds_dwordx4). LDS dest is
// wave-uniform base + lane*16; we permute the per-lane GLOBAL address so the
// content lands in the swizzled layout (same 128B lines -> still coalesced).
__device__ __forceinline__ void load_lds16(const u16* g, u16* l) {
    __builtin_amdgcn_global_load_lds(
        (const __attribute__((address_space(1))) u32*)g,
        (__attribute__((address_space(3))) u32*)l, 16, 0, 0);
}

// Explicit waitcnt encodings: simm16 = lgkmcnt<<8 | expcnt<<4 | vmcnt[3:0].
// R11 failed post-timing validation with a timing-dependent divergence; the
// DMA->barrier visibility must not depend on the compiler's barrier lowering
// emitting the vmcnt drain.  R12 proved the explicit drain; R19/R20 validated
// COUNTED vmcnt(4) across raw s_barriers on HW (passed, absmax unchanged).
// vmcnt drains oldest-first: "wait to <=4" always means "the current tile's
// 4 DMAs (and anything older, e.g. the qf loads) are done".
__device__ __forceinline__ void drain_vm() {
    __builtin_amdgcn_s_waitcnt(0x0F70);               // vmcnt(0)
}
__device__ __forceinline__ void wait_vm4() {
    __builtin_amdgcn_s_waitcnt(0x0F74);               // vmcnt(4)
}

// =====================================================================
// fp32 -> bf16 conversion: y=0 hidden [M,DM]; y=1..4 weights [DM,DM]
// =====================================================================
__global__ __launch_bounds__(256) void conv_bf16(
    const float* __restrict__ h,  const float* __restrict__ wq,
    const float* __restrict__ wk, const float* __restrict__ wv,
    const float* __restrict__ wo, u16* __restrict__ hb, u16* __restrict__ wb)
{
    const int y = blockIdx.y;
    const float* src; u16* dst; size_t n4;
    if (y == 0)      { src = h;  dst = hb;              n4 = ROWELEMS / 4; }
    else if (y == 1) { src = wq; dst = wb;              n4 = WELEMS / 4; }
    else if (y == 2) { src = wk; dst = wb + WELEMS;     n4 = WELEMS / 4; }
    else if (y == 3) { src = wv; dst = wb + 2 * WELEMS; n4 = WELEMS / 4; }
    else             { src = wo; dst = wb + 3 * WELEMS; n4 = WELEMS / 4; }
    const size_t stride = (size_t)gridDim.x * 256;
    for (size_t i = blockIdx.x * 256 + threadIdx.x; i < n4; i += stride) {
        float4 v = *(const float4*)&src[i * 4];
        u32 p0 = (u32)f2bf(v.x) | ((u32)f2bf(v.y) << 16);
        u32 p1 = (u32)f2bf(v.z) | ((u32)f2bf(v.w) << 16);
        *(uint2*)&dst[i * 4] = make_uint2(p0, p1);
    }
}

// =====================================================================
// Fused QKV GEMM + RoPE + head-major repack.
// 128x128 tile, BK=64, 2x2 waves, 16x16x32 MFMA, global_load_lds staging
// into swizzled LDS.
// Epilogue z=0/1: rope -> PAIR-INTERLEAVED Qh/Kh rows (u32 slot hd1 holds
// the rotated pair (hd1, hd1+32)); dot products are invariant under a
// fixed permutation applied to BOTH Q and K rows, so flash is unchanged.
// Epilogue z=2: transpose -> Vt[B,H,HD,S].
// =====================================================================
__global__ __launch_bounds__(256, 3) void gemm_qkv(
    const u16* __restrict__ A,
    const u16* __restrict__ W0, const u16* __restrict__ W1, const u16* __restrict__ W2,
    const float* __restrict__ b0, const float* __restrict__ b1, const float* __restrict__ b2,
    const float* __restrict__ cosT, const float* __restrict__ sinT,
    u16* __restrict__ Qh, u16* __restrict__ Kh, u16* __restrict__ Vt)
{
    __shared__ __align__(16) u16 As[128 * 64];   // 16 KB, swizzled
    __shared__ __align__(16) u16 Ws[128 * 64];   // 16 KB, swizzled

    const int tid  = threadIdx.x;
    const int wave = tid >> 6, lane = tid & 63;
    const int n16  = lane & 15, quad = lane >> 4;
    const int wm   = wave >> 1, wn = wave & 1;
    const int m0   = blockIdx.y * 128, n0 = blockIdx.x * 128;
    const int z    = blockIdx.z;

    const u16* Wz = (z == 0) ? W0 : (z == 1) ? W1 : W2;
    const float* bz = (z == 0) ? b0 : (z == 1) ? b1 : b2;

    // staging lane constants: granule g covers (r, content-group cg = slot^(r&7))
    int gao[4], ldso[4];
#pragma unroll
    for (int i = 0; i < 4; i++) {
        int g = wave * 256 + i * 64 + lane;      // 0..1023
        int r = g >> 3, cg = (g & 7) ^ (r & 7);
        gao[i]  = r * DM_ + cg * 8;
        ldso[i] = (wave * 256 + i * 64) * 8;
    }
    const u16* Ap = A  + (size_t)m0 * DM_;
    const u16* Wp = Wz + (size_t)n0 * DM_;

    floatx4 acc[4][4];
#pragma unroll
    for (int i = 0; i < 4; i++)
#pragma unroll
        for (int j = 0; j < 4; j++) acc[i][j] = (floatx4){0.f, 0.f, 0.f, 0.f};

    for (int k0 = 0; k0 < DM_; k0 += 64) {
        __syncthreads();                          // prev tile fully read
#pragma unroll
        for (int i = 0; i < 4; i++) {
            load_lds16(Ap + k0 + gao[i], &As[ldso[i]]);
            load_lds16(Wp + k0 + gao[i], &Ws[ldso[i]]);
        }
        drain_vm();                               // DMA data LDS-visible
        __syncthreads();                          // tile landed for ALL waves
#pragma unroll
        for (int ks = 0; ks < 2; ks++) {
            short8 af[4], bf[4];
#pragma unroll
            for (int t = 0; t < 4; t++) {
                af[t] = *(const short8*)&As[sw_off(wm * 64 + t * 16 + n16, ks * 4 + quad)];
                bf[t] = *(const short8*)&Ws[sw_off(wn * 64 + t * 16 + n16, ks * 4 + quad)];
            }
#pragma unroll
            for (int i = 0; i < 4; i++)
#pragma unroll
                for (int j = 0; j < 4; j++)
                    acc[i][j] = __builtin_amdgcn_mfma_f32_16x16x32_bf16(
                        af[i], bf[j], acc[i][j], 0, 0, 0);
        }
    }

    // ---- epilogue: C/D layout col = n16, row = quad*4+r ----
    if (z == 2) {
#pragma unroll
        for (int i = 0; i < 4; i++)
#pragma unroll
            for (int j = 0; j < 4; j++) {
                const int col = n0 + wn * 64 + j * 16 + n16;
                const int h = col >> 6, hd = col & 63;
                const int row0 = m0 + wm * 64 + i * 16 + quad * 4;
                const int b = row0 >> 12, s0 = row0 & 4095;
                const float bias = bz[col];
                float v0 = acc[i][j][0] + bias, v1 = acc[i][j][1] + bias;
                float v2 = acc[i][j][2] + bias, v3 = acc[i][j][3] + bias;
                u32 w0 = (u32)f2bf(v0) | ((u32)f2bf(v1) << 16);
                u32 w1 = (u32)f2bf(v2) | ((u32)f2bf(v3) << 16);
                *(uint2*)&Vt[((size_t)(b * H_ + h) * HD_ + hd) * S_ + s0] = make_uint2(w0, w1);
            }
    } else {
        u32* Out32 = (u32*)((z == 0) ? Qh : Kh);
        const float sc_ = (z == 0) ? QSC : 1.0f;
#pragma unroll
        for (int i = 0; i < 4; i++)
#pragma unroll
            for (int j = 0; j < 2; j++) {
                const int col1 = n0 + wn * 64 + j * 16 + n16;   // hd1 < 32
                const int col2 = col1 + 32;
                const int h = col1 >> 6, hd1 = col1 & 63;       // hd1 in [0,32)
                const float bias1 = bz[col1], bias2 = bz[col2];
#pragma unroll
                for (int r = 0; r < 4; r++) {
                    const int row = m0 + wm * 64 + i * 16 + quad * 4 + r;
                    const int b = row >> 12, s = row & 4095;
                    const float c  = cosT[s * HD_ + hd1];
                    const float sn = sinT[s * HD_ + hd1];
                    const float x1 = acc[i][j][r] + bias1;
                    const float x2 = acc[i][j + 2][r] + bias2;
                    const float y1 = (x1 * c - x2 * sn) * sc_;
                    const float y2 = (x2 * c + x1 * sn) * sc_;
                    // pair-interleaved: u32 slot hd1 of the 32-u32 row
                    Out32[(((size_t)(b * H_ + h) * S_ + s) << 5) + hd1] =
                        (u32)f2bf(y1) | ((u32)f2bf(y2) << 16);
                }
            }
    }
}

// =====================================================================
// Flash attention, bf16 MFMA, static softmax.
// grid (S/128, B*H) = 768 blocks = 3/CU; 64 K-tiles/block; 4 waves,
// each wave owns 32 q-rows (rt=2) -- the R17 shape.
//
// R20 structure (kept): SINGLE BARRIER PER TILE via TRIPLE BUFFER.
// Per tile: vmcnt(4) [tile t landed, t+1 in flight] -> s_barrier ->
// STAGE(t+2 into buf (t+2)%3, which the barrier just certified free)
// -> COMPUTE(t).  Buffer names STATIC (rule #20).  64 sync points;
// waves may drift a full tile apart.  106.6 -> 101.8 us.
//
// R21: T5 s_setprio around the MFMA clusters.  Post-R20 counters:
// MfmaUtil 51%, LDS ~60%, neither saturated -> overlap-quality bound.
// The catalog's regime gate says setprio pays exactly when the
// schedule has wave role diversity (null on lockstep m190; +21-39% on
// phase-split m218b/m224).  R20's single-barrier drift creates that
// diversity: waves on one SIMD sit in different phases {stage, QK-MFMA,
// exp2, PV-MFMA}.  setprio(1) on the MFMA clusters (QK and PV; exp2 and
// staging stay prio 0) lets the CU scheduler prefer the wave feeding
// the matrix pipe.  Two scalar ops per cluster, zero structural change.
//
// rho row-permutation + in-register pa packing carried from R17
// unchanged:  K staged with row shuffle rho (bits b4<-b3, b3<-b2,
// b2<-b4), so lane (n16,quad)'s S^T values ARE its PV A-fragment:
// pa[rt][ks] = {pk(sct[2ks][rt]), pk(sct[2ks+1][rt])}.  No Ps LDS.
//
// __launch_bounds__(256,3): VGPR cap 168 (R20 allocated 84).  LDS
// 48 KB -> 3 blocks/CU (grid-limited anyway).
// DO NOT raise to (256,5): R10 -> forced spill disaster.
// =====================================================================
__global__ __launch_bounds__(256, 3) void flash_mfma(
    const u16* __restrict__ Qh, const u16* __restrict__ Kh,
    const u16* __restrict__ Vt, u16* __restrict__ O)
{
    __shared__ __align__(16) u16 Ks0[64 * 64];    // 8 KB  K[named kcol][d], rho-permuted
    __shared__ __align__(16) u16 Vs0[64 * 64];    // 8 KB  V^T[d][kcol]
    __shared__ __align__(16) u16 Ks1[64 * 64];    // 8 KB  (triple buffer)
    __shared__ __align__(16) u16 Vs1[64 * 64];    // 8 KB
    __shared__ __align__(16) u16 Ks2[64 * 64];    // 8 KB
    __shared__ __align__(16) u16 Vs2[64 * 64];    // 8 KB

    const int tid  = threadIdx.x;
    const int wave = tid >> 6, lane = tid & 63;
    const int n16  = lane & 15, quad = lane >> 4;
    const int qt   = blockIdx.x;
    const int bh   = blockIdx.y;
    const size_t qk_base = (size_t)bh * S_ * HD_;
    const size_t vt_base = (size_t)bh * HD_ * S_;
    const int q0   = qt * 128;
    const int wrow = wave * 32;

    // Q fragments in registers (A/B frag layout: lane&15 x (quad*8+j))
    short8 qf[2][2];
#pragma unroll
    for (int rt = 0; rt < 2; rt++)
#pragma unroll
        for (int ks = 0; ks < 2; ks++)
            qf[rt][ks] = *(const short8*)&Qh[qk_base +
                (size_t)(q0 + wrow + rt * 16 + n16) * HD_ + ks * 32 + quad * 8];

    short8 ones;
#pragma unroll
    for (int j = 0; j < 8; j++) ones[j] = (short)0x3F80;   // bf16 1.0

    // staging lane constants (swizzled global addresses).
    // K rows permuted by rho: LDS named row n holds physical K row rho(n).
    int gk_off[2], gv_off[2], ldso[2];
#pragma unroll
    for (int i = 0; i < 2; i++) {
        int g = wave * 128 + i * 64 + lane;       // 0..511
        int r = g >> 3, cg = (g & 7) ^ (r & 7);
        int rk = (r & 0x23) | ((r & 8) << 1) | ((r & 4) << 1) | ((r & 16) >> 2);
        gk_off[i] = rk * HD_ + cg * 8;
        gv_off[i] = r  * S_  + cg * 8;
        ldso[i]   = (wave * 128 + i * 64) * 8;
    }

    floatx4 o_acc[2][4];
    floatx4 o_l[2];                   // l accumulator (ones-MFMA, C-layout)
#pragma unroll
    for (int rt = 0; rt < 2; rt++) {
        o_l[rt] = (floatx4){0.f, 0.f, 0.f, 0.f};
#pragma unroll
        for (int dt = 0; dt < 4; dt++) o_acc[rt][dt] = (floatx4){0.f, 0.f, 0.f, 0.f};
    }

    const u16* Kg = Kh + qk_base;
    const u16* Vg = Vt + vt_base;
#define KT (64 * HD_)

// stage one 64-kcol tile: 2 K DMAs + 2 V DMAs per wave (4 total)
#define STAGE(KSRC, VSRC, KDST, VDST)                                   \
    do {                                                                \
        _Pragma("unroll")                                               \
        for (int i_ = 0; i_ < 2; i_++) {                                \
            load_lds16((KSRC) + gk_off[i_], &(KDST)[ldso[i_]]);         \
            load_lds16((VSRC) + gv_off[i_], &(VDST)[ldso[i_]]);         \
        }                                                               \
    } while (0)

// R17 compute body on one tile (16 ds_read_b128, 36 MFMA, in-reg pa).
// R21: MFMA clusters wrapped in setprio(1)/(0) -- T5.
#define COMPUTE_TILE(KSB, VSB)                                          \
    do {                                                                \
        floatx4 sct[4][2];                                              \
        _Pragma("unroll")                                               \
        for (int ct = 0; ct < 4; ct++)                                  \
            _Pragma("unroll")                                           \
            for (int rt = 0; rt < 2; rt++)                              \
                sct[ct][rt] = (floatx4){0.f, 0.f, 0.f, 0.f};            \
        _Pragma("unroll")                                               \
        for (int ks = 0; ks < 2; ks++) {                                \
            short8 kf[4];                                               \
            _Pragma("unroll")                                           \
            for (int ct = 0; ct < 4; ct++)                              \
                kf[ct] = *(const short8*)&(KSB)[sw_off(ct * 16 + n16,   \
                                                       ks * 4 + quad)]; \
            __builtin_amdgcn_s_setprio(1);                              \
            _Pragma("unroll")                                           \
            for (int ct = 0; ct < 4; ct++)                              \
                _Pragma("unroll")                                       \
                for (int rt = 0; rt < 2; rt++)                          \
                    sct[ct][rt] = __builtin_amdgcn_mfma_f32_16x16x32_bf16( \
                        kf[ct], qf[rt][ks], sct[ct][rt], 0, 0, 0);      \
            __builtin_amdgcn_s_setprio(0);                              \
        }                                                               \
        short8 pa[2][2];                                                \
        _Pragma("unroll")                                               \
        for (int rt = 0; rt < 2; rt++)                                  \
            _Pragma("unroll")                                           \
            for (int ks = 0; ks < 2; ks++) {                            \
                const floatx4 lo = sct[2 * ks][rt];                     \
                const floatx4 hi = sct[2 * ks + 1][rt];                 \
                uint32x4 w;                                             \
                w[0] = pk_trunc(__builtin_amdgcn_exp2f(lo[0]),          \
                                __builtin_amdgcn_exp2f(lo[1]));         \
                w[1] = pk_trunc(__builtin_amdgcn_exp2f(lo[2]),          \
                                __builtin_amdgcn_exp2f(lo[3]));         \
                w[2] = pk_trunc(__builtin_amdgcn_exp2f(hi[0]),          \
                                __builtin_amdgcn_exp2f(hi[1]));         \
                w[3] = pk_trunc(__builtin_amdgcn_exp2f(hi[2]),          \
                                __builtin_amdgcn_exp2f(hi[3]));         \
                pa[rt][ks] = __builtin_bit_cast(short8, w);             \
            }                                                           \
        _Pragma("unroll")                                               \
        for (int ks = 0; ks < 2; ks++) {                                \
            short8 vb[4];                                               \
            _Pragma("unroll")                                           \
            for (int dt = 0; dt < 4; dt++)                              \
                vb[dt] = *(const short8*)&(VSB)[sw_off(dt * 16 + n16,   \
                                                       ks * 4 + quad)]; \
            __builtin_amdgcn_s_setprio(1);                              \
            _Pragma("unroll")                                           \
            for (int rt = 0; rt < 2; rt++) {                            \
                _Pragma("unroll")                                       \
                for (int dt = 0; dt < 4; dt++)                          \
                    o_acc[rt][dt] = __builtin_amdgcn_mfma_f32_16x16x32_bf16( \
                        pa[rt][ks], vb[dt], o_acc[rt][dt], 0, 0, 0);    \
                o_l[rt] = __builtin_amdgcn_mfma_f32_16x16x32_bf16(      \
                    pa[rt][ks], ones, o_l[rt], 0, 0, 0);                \
            }                                                           \
            __builtin_amdgcn_s_setprio(0);                              \
        }                                                               \
    } while (0)

    // ---- prologue: tiles 0,1 -> buffers 0,1 ----
    STAGE(Kg,      Vg,      Ks0, Vs0);
    STAGE(Kg + KT, Vg + 64, Ks1, Vs1);

    // t = 3g+p computes buf p%3 and stages t+2 -> buf (t+2)%3.
    // 21 groups cover t = 0..62; tile 63 handled in the epilogue iter.
    for (int g = 0; g < 21; ++g) {
        // -- t = 3g: compute b0, stage t+2 -> b2 --
        wait_vm4();                               // tile t landed; t+1 in flight
        __builtin_amdgcn_s_barrier();             // t visible; compute(t-1) done by ALL
        STAGE(Kg + 2 * KT, Vg + 2 * 64, Ks2, Vs2);
        COMPUTE_TILE(Ks0, Vs0);
        Kg += KT; Vg += 64;

        // -- t = 3g+1: compute b1, stage t+2 -> b0 --
        wait_vm4();
        __builtin_amdgcn_s_barrier();
        STAGE(Kg + 2 * KT, Vg + 2 * 64, Ks0, Vs0);
        COMPUTE_TILE(Ks1, Vs1);
        Kg += KT; Vg += 64;

        // -- t = 3g+2: compute b2, stage t+2 -> b1 (except t=62: t+2=64) --
        wait_vm4();
        __builtin_amdgcn_s_barrier();
        if (g < 20)
            STAGE(Kg + 2 * KT, Vg + 2 * 64, Ks1, Vs1);
        COMPUTE_TILE(Ks2, Vs2);
        Kg += KT; Vg += 64;
    }
    // -- t = 63: compute b0 (staged at t=61) --
    drain_vm();                                   // last tile fully landed
    __builtin_amdgcn_s_barrier();
    COMPUTE_TILE(Ks0, Vs0);
#undef STAGE
#undef COMPUTE_TILE
#undef KT

    // ---- epilogue: normalize by complete l (C-layout: row=quad*4+r, all
    // cols equal, so every lane holds its row's l) and write final bf16 O ----
    const int b = bh / H_, h = bh % H_;
#pragma unroll
    for (int rt = 0; rt < 2; rt++)
#pragma unroll
        for (int r = 0; r < 4; r++) {
            const float inv = 1.0f / o_l[rt][r];
            const int srow = q0 + wrow + rt * 16 + quad * 4 + r;
            u16* Orow = O + ((size_t)b * S_ + srow) * DM_ + h * HD_;
#pragma unroll
            for (int dt = 0; dt < 4; dt++)
                Orow[dt * 16 + n16] = f2bf(o_acc[rt][dt][r] * inv);
        }
}

// =====================================================================
// Out-proj GEMM, pure DMA-staged (R14: flash output is pre-normalized):
//   out = A @ Wo^T + hidden (fp32).  A and W both via global_load_lds.
// Tile 64(m) x 128(n), BK=64, 2x2 waves (wave: 32 rows x 64 cols).
// =====================================================================
__global__ __launch_bounds__(256, 4) void gemm_out(
    const u16* __restrict__ A, const u16* __restrict__ W,
    const float* __restrict__ resid, float* __restrict__ Cf)
{
    __shared__ __align__(16) u16 As[64 * 64];     //  8 KB, swizzled
    __shared__ __align__(16) u16 Ws[128 * 64];    // 16 KB, swizzled

    const int tid  = threadIdx.x;
    const int wave = tid >> 6, lane = tid & 63;
    const int n16  = lane & 15, quad = lane >> 4;
    const int wm   = wave >> 1, wn = wave & 1;
    const int m0   = blockIdx.y * 64, n0 = blockIdx.x * 128;

    // W: 1024 granules (4 DMA/thread); A: 512 granules (2 DMA/thread)
    int gwo[4], ldswo[4], gao[2], ldsao[2];
#pragma unroll
    for (int i = 0; i < 4; i++) {
        int g = wave * 256 + i * 64 + lane;
        int r = g >> 3, cg = (g & 7) ^ (r & 7);
        gwo[i]   = r * DM_ + cg * 8;
        ldswo[i] = (wave * 256 + i * 64) * 8;
    }
#pragma unroll
    for (int i = 0; i < 2; i++) {
        int g = wave * 128 + i * 64 + lane;       // 0..511
        int r = g >> 3, cg = (g & 7) ^ (r & 7);
        gao[i]   = r * DM_ + cg * 8;
        ldsao[i] = (wave * 128 + i * 64) * 8;
    }
    const u16* Wp = W + (size_t)n0 * DM_;
    const u16* Ap = A + (size_t)m0 * DM_;

    floatx4 acc[2][4];
#pragma unroll
    for (int i = 0; i < 2; i++)
#pragma unroll
        for (int j = 0; j < 4; j++) acc[i][j] = (floatx4){0.f, 0.f, 0.f, 0.f};

    for (int k0 = 0; k0 < DM_; k0 += 64) {
        __syncthreads();
#pragma unroll
        for (int i = 0; i < 4; i++)
            load_lds16(Wp + k0 + gwo[i], &Ws[ldswo[i]]);
#pragma unroll
        for (int i = 0; i < 2; i++)
            load_lds16(Ap + k0 + gao[i], &As[ldsao[i]]);
        drain_vm();                               // DMA data LDS-visible
        __syncthreads();

#pragma unroll
        for (int ks = 0; ks < 2; ks++) {
            short8 af[2], bf[4];
#pragma unroll
            for (int rt = 0; rt < 2; rt++)
                af[rt] = *(const short8*)&As[sw_off(wm * 32 + rt * 16 + n16, ks * 4 + quad)];
#pragma unroll
            for (int ct = 0; ct < 4; ct++)
                bf[ct] = *(const short8*)&Ws[sw_off(wn * 64 + ct * 16 + n16, ks * 4 + quad)];
#pragma unroll
            for (int rt = 0; rt < 2; rt++)
#pragma unroll
                for (int ct = 0; ct < 4; ct++)
                    acc[rt][ct] = __builtin_amdgcn_mfma_f32_16x16x32_bf16(
                        af[rt], bf[ct], acc[rt][ct], 0, 0, 0);
        }
    }

#pragma unroll
    for (int rt = 0; rt < 2; rt++)
#pragma unroll
        for (int ct = 0; ct < 4; ct++) {
            const int col = n0 + wn * 64 + ct * 16 + n16;
#pragma unroll
            for (int r = 0; r < 4; r++) {
                const int row = m0 + wm * 32 + rt * 16 + quad * 4 + r;
                Cf[(size_t)row * DM_ + col] = acc[rt][ct][r] + resid[(size_t)row * DM_ + col];
            }
        }
}

// =====================================================================
// LayerNorm in-place on [M, DM] rows. grid: M, block: 256 (R12-proven)
// =====================================================================
__global__ __launch_bounds__(256) void ln_kernel(
    float* __restrict__ io, const float* __restrict__ g, const float* __restrict__ bb)
{
    const int row = blockIdx.x, t = threadIdx.x;
    float* p = io + (size_t)row * DM_;
    float x[3];
    float sum = 0.0f, sq = 0.0f;
#pragma unroll
    for (int i = 0; i < 3; i++) {
        x[i] = p[t + i * 256];
        sum += x[i];
        sq  = fmaf(x[i], x[i], sq);
    }
#pragma unroll
    for (int off = 32; off >= 1; off >>= 1) {
        sum += __shfl_xor(sum, off);
        sq  += __shfl_xor(sq, off);
    }
    __shared__ float s1[4], s2[4];
    if ((t & 63) == 0) { s1[t >> 6] = sum; s2[t >> 6] = sq; }
    __syncthreads();
    sum = s1[0] + s1[1] + s1[2] + s1[3];
    sq  = s2[0] + s2[1] + s2[2] + s2[3];
    const float mu  = sum * (1.0f / 768.0f);
    const float var = sq * (1.0f / 768.0f) - mu * mu;
    const float rs  = rsqrtf(var + 1e-12f);
#pragma unroll
    for (int i = 0; i < 3; i++) {
        const int c = t + i * 256;
        p[c] = (x[i] - mu) * rs * g[c] + bb[c];
    }
}

// =====================================================================
// Workspace (bf16 elem offsets; total ~55.5 MB <= proven 75.5 MB):
//   Hb [0,R)      -> O (final attn out, bf16) overlays after gemm_qkv
//   Wb [R, R+4W)
//   Qh, Kh, Vt    (R each)
// =====================================================================
extern "C" void kernel_launch(void* const* d_in, const int* in_sizes, int n_in,
                              void* d_out, int out_size, void* d_ws, size_t ws_size,
                              hipStream_t stream)
{
    const float* hidden = (const float*)d_in[0];
    const float* cosT   = (const float*)d_in[1];
    const float* sinT   = (const float*)d_in[2];
    const float* Wq     = (const float*)d_in[3];
    const float* bq     = (const float*)d_in[4];
    const float* Wk     = (const float*)d_in[5];
    const float* bk     = (const float*)d_in[6];
    const float* Wv     = (const float*)d_in[7];
    const float* bv     = (const float*)d_in[8];
    const float* Wo     = (const float*)d_in[9];
    const float* ln_g   = (const float*)d_in[10];
    const float* ln_b   = (const float*)d_in[11];
    float* out = (float*)d_out;

    u16* wsb = (u16*)d_ws;
    u16* Hb  = wsb;
    u16* Wb  = wsb + ROWELEMS;
    u16* Qh  = Wb + 4 * WELEMS;
    u16* Kh  = Qh + ROWELEMS;
    u16* Vt  = Kh + ROWELEMS;
    u16* Ob  = Hb;                        // overlays Hb (dead after gemm_qkv)
    u16* Wqb = Wb, *Wkb = Wb + WELEMS, *Wvb = Wb + 2 * WELEMS, *Wob = Wb + 3 * WELEMS;

    conv_bf16<<<dim3(1024, 5), 256, 0, stream>>>(hidden, Wq, Wk, Wv, Wo, Hb, Wb);

    gemm_qkv<<<dim3(DM_ / 128, M_ / 128, 3), 256, 0, stream>>>(
        Hb, Wqb, Wkb, Wvb, bq, bk, bv, cosT, sinT, Qh, Kh, Vt);

    flash_mfma<<<dim3(S_ / 128, B_ * H_), 256, 0, stream>>>(Qh, Kh, Vt, Ob);

    gemm_out<<<dim3(DM_ / 128, M_ / 64), 256, 0, stream>>>(Ob, Wob, hidden, out);

    ln_kernel<<<M_, 256, 0, stream>>>(out, ln_g, ln_b);
}

// Round 10
// 265.577 us; speedup vs baseline: 1.1117x; 1.0216x over previous
//
#include <hip/hip_runtime.h>
#include <math.h>

// Problem constants (NomicBertAttention): B=2, S=4096, DM=768, H=12, HD=64
#define B_   2
#define S_   4096
#define DM_  768
#define H_   12
#define HD_  64
#define M_   (B_ * S_)                 // 8192 rows
#define ROWELEMS ((size_t)M_ * DM_)    // 6291456 elems per [M,DM] buffer
#define WELEMS  ((size_t)DM_ * DM_)    // 589824 elems per weight

// net softmax scale: SCALING*SCALING = 1/64, times log2(e) so v_exp_f32 (2^x)
// computes e^(score/64) directly.  Folded into Q in the QKV-GEMM epilogue.
#define QSC (1.4426950408889634f / 64.0f)

typedef unsigned short u16;
typedef unsigned int   u32;
typedef __attribute__((ext_vector_type(8))) short  short8;   // 8 x bf16 (4 VGPR)
typedef __attribute__((ext_vector_type(4))) float  floatx4;  // MFMA accumulator
typedef __attribute__((ext_vector_type(4))) u32    uint32x4;

__device__ inline u16 f2bf(float f) {                 // RNE round
    u32 u = __builtin_bit_cast(u32, f);
    u += 0x7FFF + ((u >> 16) & 1);
    return (u16)(u >> 16);
}
__device__ inline float bf2f(u16 h) {
    return __builtin_bit_cast(float, (u32)h << 16);
}
__device__ inline u32 pk_trunc(float a, float b) {    // [bf16(b)<<16 | bf16(a)], truncate
    return __builtin_amdgcn_perm(__builtin_bit_cast(u32, b),
                                 __builtin_bit_cast(u32, a), 0x07060302);
}

// XOR-swizzled LDS offset, pitch 64 bf16 (128 B) rows:
// element (r, c) lives at r*64 + ((c/8 ^ (r&7))*8) + c%8.
__device__ inline int sw_off(int r, int cg) {         // cg = c>>3 (8-elem group)
    return (r << 6) + ((cg ^ (r & 7)) << 3);
}

// Async global->LDS 16B DMA (global_load_lds_dwordx4). LDS dest is
// wave-uniform base + lane*16; we permute the per-lane GLOBAL address so the
// content lands in the swizzled layout (same 128B lines -> still coalesced).
__device__ __forceinline__ void load_lds16(const u16* g, u16* l) {
    __builtin_amdgcn_global_load_lds(
        (const __attribute__((address_space(1))) u32*)g,
        (__attribute__((address_space(3))) u32*)l, 16, 0, 0);
}

// Explicit waitcnt encodings: simm16 = lgkmcnt<<8 | expcnt<<4 | vmcnt[3:0].
// R11 failed post-timing validation with a timing-dependent divergence; the
// DMA->barrier visibility must not depend on the compiler's barrier lowering
// emitting the vmcnt drain.  R12 proved the explicit drain; R19/R20 validated
// COUNTED vmcnt(4) across raw s_barriers on HW (passed, absmax unchanged).
// vmcnt drains oldest-first: "wait to <=4" always means "the current tile's
// 4 DMAs (and anything older, e.g. the qf loads) are done".
__device__ __forceinline__ void drain_vm() {
    __builtin_amdgcn_s_waitcnt(0x0F70);               // vmcnt(0)
}
__device__ __forceinline__ void wait_vm4() {
    __builtin_amdgcn_s_waitcnt(0x0F74);               // vmcnt(4)
}

// =====================================================================
// fp32 -> bf16 conversion: y=0 hidden [M,DM]; y=1..4 weights [DM,DM]
// =====================================================================
__global__ __launch_bounds__(256) void conv_bf16(
    const float* __restrict__ h,  const float* __restrict__ wq,
    const float* __restrict__ wk, const float* __restrict__ wv,
    const float* __restrict__ wo, u16* __restrict__ hb, u16* __restrict__ wb)
{
    const int y = blockIdx.y;
    const float* src; u16* dst; size_t n4;
    if (y == 0)      { src = h;  dst = hb;              n4 = ROWELEMS / 4; }
    else if (y == 1) { src = wq; dst = wb;              n4 = WELEMS / 4; }
    else if (y == 2) { src = wk; dst = wb + WELEMS;     n4 = WELEMS / 4; }
    else if (y == 3) { src = wv; dst = wb + 2 * WELEMS; n4 = WELEMS / 4; }
    else             { src = wo; dst = wb + 3 * WELEMS; n4 = WELEMS / 4; }
    const size_t stride = (size_t)gridDim.x * 256;
    for (size_t i = blockIdx.x * 256 + threadIdx.x; i < n4; i += stride) {
        float4 v = *(const float4*)&src[i * 4];
        u32 p0 = (u32)f2bf(v.x) | ((u32)f2bf(v.y) << 16);
        u32 p1 = (u32)f2bf(v.z) | ((u32)f2bf(v.w) << 16);
        *(uint2*)&dst[i * 4] = make_uint2(p0, p1);
    }
}

// =====================================================================
// Fused QKV GEMM + RoPE + head-major repack.
// R22: tile 128(m) x 192(n), BK=64 -- grid (768/192=4, 64, 3) = 768
// blocks = EXACTLY 3/CU (the old 128x128 tiling gave 1152 blocks =
// 1.5 scheduling rounds; the second round ran 384 blocks on half the
// machine, ~15-20% of this kernel's time).  Waves: 4 split along M,
// each wave owns 32 rows x 192 cols (acc[2][12] = 96 VGPR; bf reads
// chunked in 6s to cap live regs ~145 < 168).  RoPE pairing intact:
// each 64-col head = 4 j-tiles, all inside the wave's 192 cols (x1 at
// j%4 in {0,1}, partner j+2).  LDS As 16 KB + Ws 24 KB = 40 KB -> 3
// blocks/CU.  Proven 2-barrier drain loop (R12) kept.
// Epilogue z=0/1: rope -> PAIR-INTERLEAVED Qh/Kh rows (u32 slot hd1
// holds the rotated pair (hd1, hd1+32)).  z=2: transpose -> Vt.
// =====================================================================
__global__ __launch_bounds__(256, 3) void gemm_qkv(
    const u16* __restrict__ A,
    const u16* __restrict__ W0, const u16* __restrict__ W1, const u16* __restrict__ W2,
    const float* __restrict__ b0, const float* __restrict__ b1, const float* __restrict__ b2,
    const float* __restrict__ cosT, const float* __restrict__ sinT,
    u16* __restrict__ Qh, u16* __restrict__ Kh, u16* __restrict__ Vt)
{
    __shared__ __align__(16) u16 As[128 * 64];   // 16 KB, swizzled
    __shared__ __align__(16) u16 Ws[192 * 64];   // 24 KB, swizzled

    const int tid  = threadIdx.x;
    const int wave = tid >> 6, lane = tid & 63;
    const int n16  = lane & 15, quad = lane >> 4;
    const int m0   = blockIdx.y * 128, n0 = blockIdx.x * 192;
    const int z    = blockIdx.z;

    const u16* Wz = (z == 0) ? W0 : (z == 1) ? W1 : W2;
    const float* bz = (z == 0) ? b0 : (z == 1) ? b1 : b2;

    // staging lane constants: granule g covers (r, content-group cg = slot^(r&7))
    // A: 1024 granules (4/thread); W: 1536 granules (6/thread)
    int gao[4], ldsao[4], gwo[6], ldswo[6];
#pragma unroll
    for (int i = 0; i < 4; i++) {
        int g = wave * 256 + i * 64 + lane;      // 0..1023
        int r = g >> 3, cg = (g & 7) ^ (r & 7);
        gao[i]   = r * DM_ + cg * 8;
        ldsao[i] = (wave * 256 + i * 64) * 8;
    }
#pragma unroll
    for (int i = 0; i < 6; i++) {
        int g = wave * 384 + i * 64 + lane;      // 0..1535
        int r = g >> 3, cg = (g & 7) ^ (r & 7);
        gwo[i]   = r * DM_ + cg * 8;
        ldswo[i] = (wave * 384 + i * 64) * 8;
    }
    const u16* Ap = A  + (size_t)m0 * DM_;
    const u16* Wp = Wz + (size_t)n0 * DM_;

    floatx4 acc[2][12];
#pragma unroll
    for (int i = 0; i < 2; i++)
#pragma unroll
        for (int j = 0; j < 12; j++) acc[i][j] = (floatx4){0.f, 0.f, 0.f, 0.f};

    for (int k0 = 0; k0 < DM_; k0 += 64) {
        __syncthreads();                          // prev tile fully read
#pragma unroll
        for (int i = 0; i < 4; i++)
            load_lds16(Ap + k0 + gao[i], &As[ldsao[i]]);
#pragma unroll
        for (int i = 0; i < 6; i++)
            load_lds16(Wp + k0 + gwo[i], &Ws[ldswo[i]]);
        drain_vm();                               // DMA data LDS-visible
        __syncthreads();                          // tile landed for ALL waves
#pragma unroll
        for (int ks = 0; ks < 2; ks++) {
            short8 af[2];
#pragma unroll
            for (int t = 0; t < 2; t++)
                af[t] = *(const short8*)&As[sw_off(wave * 32 + t * 16 + n16, ks * 4 + quad)];
#pragma unroll
            for (int jh = 0; jh < 2; jh++) {      // chunk bf in 6s (VGPR cap)
                short8 bf[6];
#pragma unroll
                for (int j = 0; j < 6; j++)
                    bf[j] = *(const short8*)&Ws[sw_off((jh * 6 + j) * 16 + n16, ks * 4 + quad)];
#pragma unroll
                for (int i = 0; i < 2; i++)
#pragma unroll
                    for (int j = 0; j < 6; j++)
                        acc[i][jh * 6 + j] = __builtin_amdgcn_mfma_f32_16x16x32_bf16(
                            af[i], bf[j], acc[i][jh * 6 + j], 0, 0, 0);
            }
        }
    }

    // ---- epilogue: C/D layout col = n16, row = quad*4+r ----
    if (z == 2) {
#pragma unroll
        for (int i = 0; i < 2; i++)
#pragma unroll
            for (int j = 0; j < 12; j++) {
                const int col = n0 + j * 16 + n16;
                const int h = col >> 6, hd = col & 63;
                const int row0 = m0 + wave * 32 + i * 16 + quad * 4;
                const int b = row0 >> 12, s0 = row0 & 4095;
                const float bias = bz[col];
                float v0 = acc[i][j][0] + bias, v1 = acc[i][j][1] + bias;
                float v2 = acc[i][j][2] + bias, v3 = acc[i][j][3] + bias;
                u32 w0 = (u32)f2bf(v0) | ((u32)f2bf(v1) << 16);
                u32 w1 = (u32)f2bf(v2) | ((u32)f2bf(v3) << 16);
                *(uint2*)&Vt[((size_t)(b * H_ + h) * HD_ + hd) * S_ + s0] = make_uint2(w0, w1);
            }
    } else {
        u32* Out32 = (u32*)((z == 0) ? Qh : Kh);
        const float sc_ = (z == 0) ? QSC : 1.0f;
#pragma unroll
        for (int i = 0; i < 2; i++)
#pragma unroll
            for (int jp = 0; jp < 6; jp++) {
                const int j1 = (jp >> 1) * 4 + (jp & 1);   // {0,1,4,5,8,9}: x1 tiles
                const int col1 = n0 + j1 * 16 + n16;
                const int h = col1 >> 6, hd1 = col1 & 63;  // hd1 in [0,32)
                const float bias1 = bz[col1], bias2 = bz[col1 + 32];
#pragma unroll
                for (int r = 0; r < 4; r++) {
                    const int row = m0 + wave * 32 + i * 16 + quad * 4 + r;
                    const int b = row >> 12, s = row & 4095;
                    const float c  = cosT[s * HD_ + hd1];
                    const float sn = sinT[s * HD_ + hd1];
                    const float x1 = acc[i][j1][r] + bias1;
                    const float x2 = acc[i][j1 + 2][r] + bias2;
                    const float y1 = (x1 * c - x2 * sn) * sc_;
                    const float y2 = (x2 * c + x1 * sn) * sc_;
                    // pair-interleaved: u32 slot hd1 of the 32-u32 row
                    Out32[(((size_t)(b * H_ + h) * S_ + s) << 5) + hd1] =
                        (u32)f2bf(y1) | ((u32)f2bf(y2) << 16);
                }
            }
    }
}

// =====================================================================
// Flash attention, bf16 MFMA, static softmax.
// grid (S/128, B*H) = 768 blocks = 3/CU; 64 K-tiles/block; 4 waves,
// each wave owns 32 q-rows (rt=2) -- the R17 shape.
//
// R20 structure (FINAL for this shape): SINGLE BARRIER PER TILE via
// TRIPLE BUFFER.  Per tile: vmcnt(4) [tile t landed, t+1 in flight] ->
// s_barrier -> STAGE(t+2 into buf (t+2)%3, which the barrier just
// certified free) -> COMPUTE(t).  Buffer names STATIC (rule #20).
// 64 sync points; waves may drift a full tile apart.  106.6 -> 101.8us.
// R21's setprio was NULL (+1us) -> reverted.  Counters at R20: MfmaUtil
// 51%, VALU 47%, LDS ~57%, all sub-saturated -> dependency-overlap
// bound; R18 proved rt=4 trades occupancy at a net loss, R19 proved
// DMA latency is covered.  Declared done at this structure.
//
// rho row-permutation + in-register pa packing carried from R17
// unchanged:  K staged with row shuffle rho (bits b4<-b3, b3<-b2,
// b2<-b4), so lane (n16,quad)'s S^T values ARE its PV A-fragment:
// pa[rt][ks] = {pk(sct[2ks][rt]), pk(sct[2ks+1][rt])}.  No Ps LDS.
//
// __launch_bounds__(256,3): VGPR cap 168 (R20 allocated 84).  LDS
// 48 KB -> 3 blocks/CU (grid-limited anyway).
// DO NOT raise to (256,5): R10 -> forced spill disaster.
// =====================================================================
__global__ __launch_bounds__(256, 3) void flash_mfma(
    const u16* __restrict__ Qh, const u16* __restrict__ Kh,
    const u16* __restrict__ Vt, u16* __restrict__ O)
{
    __shared__ __align__(16) u16 Ks0[64 * 64];    // 8 KB  K[named kcol][d], rho-permuted
    __shared__ __align__(16) u16 Vs0[64 * 64];    // 8 KB  V^T[d][kcol]
    __shared__ __align__(16) u16 Ks1[64 * 64];    // 8 KB  (triple buffer)
    __shared__ __align__(16) u16 Vs1[64 * 64];    // 8 KB
    __shared__ __align__(16) u16 Ks2[64 * 64];    // 8 KB
    __shared__ __align__(16) u16 Vs2[64 * 64];    // 8 KB

    const int tid  = threadIdx.x;
    const int wave = tid >> 6, lane = tid & 63;
    const int n16  = lane & 15, quad = lane >> 4;
    const int qt   = blockIdx.x;
    const int bh   = blockIdx.y;
    const size_t qk_base = (size_t)bh * S_ * HD_;
    const size_t vt_base = (size_t)bh * HD_ * S_;
    const int q0   = qt * 128;
    const int wrow = wave * 32;

    // Q fragments in registers (A/B frag layout: lane&15 x (quad*8+j))
    short8 qf[2][2];
#pragma unroll
    for (int rt = 0; rt < 2; rt++)
#pragma unroll
        for (int ks = 0; ks < 2; ks++)
            qf[rt][ks] = *(const short8*)&Qh[qk_base +
                (size_t)(q0 + wrow + rt * 16 + n16) * HD_ + ks * 32 + quad * 8];

    short8 ones;
#pragma unroll
    for (int j = 0; j < 8; j++) ones[j] = (short)0x3F80;   // bf16 1.0

    // staging lane constants (swizzled global addresses).
    // K rows permuted by rho: LDS named row n holds physical K row rho(n).
    int gk_off[2], gv_off[2], ldso[2];
#pragma unroll
    for (int i = 0; i < 2; i++) {
        int g = wave * 128 + i * 64 + lane;       // 0..511
        int r = g >> 3, cg = (g & 7) ^ (r & 7);
        int rk = (r & 0x23) | ((r & 8) << 1) | ((r & 4) << 1) | ((r & 16) >> 2);
        gk_off[i] = rk * HD_ + cg * 8;
        gv_off[i] = r  * S_  + cg * 8;
        ldso[i]   = (wave * 128 + i * 64) * 8;
    }

    floatx4 o_acc[2][4];
    floatx4 o_l[2];                   // l accumulator (ones-MFMA, C-layout)
#pragma unroll
    for (int rt = 0; rt < 2; rt++) {
        o_l[rt] = (floatx4){0.f, 0.f, 0.f, 0.f};
#pragma unroll
        for (int dt = 0; dt < 4; dt++) o_acc[rt][dt] = (floatx4){0.f, 0.f, 0.f, 0.f};
    }

    const u16* Kg = Kh + qk_base;
    const u16* Vg = Vt + vt_base;
#define KT (64 * HD_)

// stage one 64-kcol tile: 2 K DMAs + 2 V DMAs per wave (4 total)
#define STAGE(KSRC, VSRC, KDST, VDST)                                   \
    do {                                                                \
        _Pragma("unroll")                                               \
        for (int i_ = 0; i_ < 2; i_++) {                                \
            load_lds16((KSRC) + gk_off[i_], &(KDST)[ldso[i_]]);         \
            load_lds16((VSRC) + gv_off[i_], &(VDST)[ldso[i_]]);         \
        }                                                               \
    } while (0)

// R17 compute body on one tile (16 ds_read_b128, 36 MFMA, in-reg pa)
#define COMPUTE_TILE(KSB, VSB)                                          \
    do {                                                                \
        floatx4 sct[4][2];                                              \
        _Pragma("unroll")                                               \
        for (int ct = 0; ct < 4; ct++)                                  \
            _Pragma("unroll")                                           \
            for (int rt = 0; rt < 2; rt++)                              \
                sct[ct][rt] = (floatx4){0.f, 0.f, 0.f, 0.f};            \
        _Pragma("unroll")                                               \
        for (int ks = 0; ks < 2; ks++) {                                \
            short8 kf[4];                                               \
            _Pragma("unroll")                                           \
            for (int ct = 0; ct < 4; ct++)                              \
                kf[ct] = *(const short8*)&(KSB)[sw_off(ct * 16 + n16,   \
                                                       ks * 4 + quad)]; \
            _Pragma("unroll")                                           \
            for (int ct = 0; ct < 4; ct++)                              \
                _Pragma("unroll")                                       \
                for (int rt = 0; rt < 2; rt++)                          \
                    sct[ct][rt] = __builtin_amdgcn_mfma_f32_16x16x32_bf16( \
                        kf[ct], qf[rt][ks], sct[ct][rt], 0, 0, 0);      \
        }                                                               \
        short8 pa[2][2];                                                \
        _Pragma("unroll")                                               \
        for (int rt = 0; rt < 2; rt++)                                  \
            _Pragma("unroll")                                           \
            for (int ks = 0; ks < 2; ks++) {                            \
                const floatx4 lo = sct[2 * ks][rt];                     \
                const floatx4 hi = sct[2 * ks + 1][rt];                 \
                uint32x4 w;                                             \
                w[0] = pk_trunc(__builtin_amdgcn_exp2f(lo[0]),          \
                                __builtin_amdgcn_exp2f(lo[1]));         \
                w[1] = pk_trunc(__builtin_amdgcn_exp2f(lo[2]),          \
                                __builtin_amdgcn_exp2f(lo[3]));         \
                w[2] = pk_trunc(__builtin_amdgcn_exp2f(hi[0]),          \
                                __builtin_amdgcn_exp2f(hi[1]));         \
                w[3] = pk_trunc(__builtin_amdgcn_exp2f(hi[2]),          \
                                __builtin_amdgcn_exp2f(hi[3]));         \
                pa[rt][ks] = __builtin_bit_cast(short8, w);             \
            }                                                           \
        _Pragma("unroll")                                               \
        for (int ks = 0; ks < 2; ks++) {                                \
            short8 vb[4];                                               \
            _Pragma("unroll")                                           \
            for (int dt = 0; dt < 4; dt++)                              \
                vb[dt] = *(const short8*)&(VSB)[sw_off(dt * 16 + n16,   \
                                                       ks * 4 + quad)]; \
            _Pragma("unroll")                                           \
            for (int rt = 0; rt < 2; rt++) {                            \
                _Pragma("unroll")                                       \
                for (int dt = 0; dt < 4; dt++)                          \
                    o_acc[rt][dt] = __builtin_amdgcn_mfma_f32_16x16x32_bf16( \
                        pa[rt][ks], vb[dt], o_acc[rt][dt], 0, 0, 0);    \
                o_l[rt] = __builtin_amdgcn_mfma_f32_16x16x32_bf16(      \
                    pa[rt][ks], ones, o_l[rt], 0, 0, 0);                \
            }                                                           \
        }                                                               \
    } while (0)

    // ---- prologue: tiles 0,1 -> buffers 0,1 ----
    STAGE(Kg,      Vg,      Ks0, Vs0);
    STAGE(Kg + KT, Vg + 64, Ks1, Vs1);

    // t = 3g+p computes buf p%3 and stages t+2 -> buf (t+2)%3.
    // 21 groups cover t = 0..62; tile 63 handled in the epilogue iter.
    for (int g = 0; g < 21; ++g) {
        // -- t = 3g: compute b0, stage t+2 -> b2 --
        wait_vm4();                               // tile t landed; t+1 in flight
        __builtin_amdgcn_s_barrier();             // t visible; compute(t-1) done by ALL
        STAGE(Kg + 2 * KT, Vg + 2 * 64, Ks2, Vs2);
        COMPUTE_TILE(Ks0, Vs0);
        Kg += KT; Vg += 64;

        // -- t = 3g+1: compute b1, stage t+2 -> b0 --
        wait_vm4();
        __builtin_amdgcn_s_barrier();
        STAGE(Kg + 2 * KT, Vg + 2 * 64, Ks0, Vs0);
        COMPUTE_TILE(Ks1, Vs1);
        Kg += KT; Vg += 64;

        // -- t = 3g+2: compute b2, stage t+2 -> b1 (except t=62: t+2=64) --
        wait_vm4();
        __builtin_amdgcn_s_barrier();
        if (g < 20)
            STAGE(Kg + 2 * KT, Vg + 2 * 64, Ks1, Vs1);
        COMPUTE_TILE(Ks2, Vs2);
        Kg += KT; Vg += 64;
    }
    // -- t = 63: compute b0 (staged at t=61) --
    drain_vm();                                   // last tile fully landed
    __builtin_amdgcn_s_barrier();
    COMPUTE_TILE(Ks0, Vs0);
#undef STAGE
#undef COMPUTE_TILE
#undef KT

    // ---- epilogue: normalize by complete l (C-layout: row=quad*4+r, all
    // cols equal, so every lane holds its row's l) and write final bf16 O ----
    const int b = bh / H_, h = bh % H_;
#pragma unroll
    for (int rt = 0; rt < 2; rt++)
#pragma unroll
        for (int r = 0; r < 4; r++) {
            const float inv = 1.0f / o_l[rt][r];
            const int srow = q0 + wrow + rt * 16 + quad * 4 + r;
            u16* Orow = O + ((size_t)b * S_ + srow) * DM_ + h * HD_;
#pragma unroll
            for (int dt = 0; dt < 4; dt++)
                Orow[dt * 16 + n16] = f2bf(o_acc[rt][dt][r] * inv);
        }
}

// =====================================================================
// Out-proj GEMM, pure DMA-staged (R14: flash output is pre-normalized):
//   out = A @ Wo^T + hidden (fp32).  A and W both via global_load_lds.
// Tile 64(m) x 128(n), BK=64, 2x2 waves (wave: 32 rows x 64 cols).
// =====================================================================
__global__ __launch_bounds__(256, 4) void gemm_out(
    const u16* __restrict__ A, const u16* __restrict__ W,
    const float* __restrict__ resid, float* __restrict__ Cf)
{
    __shared__ __align__(16) u16 As[64 * 64];     //  8 KB, swizzled
    __shared__ __align__(16) u16 Ws[128 * 64];    // 16 KB, swizzled

    const int tid  = threadIdx.x;
    const int wave = tid >> 6, lane = tid & 63;
    const int n16  = lane & 15, quad = lane >> 4;
    const int wm   = wave >> 1, wn = wave & 1;
    const int m0   = blockIdx.y * 64, n0 = blockIdx.x * 128;

    // W: 1024 granules (4 DMA/thread); A: 512 granules (2 DMA/thread)
    int gwo[4], ldswo[4], gao[2], ldsao[2];
#pragma unroll
    for (int i = 0; i < 4; i++) {
        int g = wave * 256 + i * 64 + lane;
        int r = g >> 3, cg = (g & 7) ^ (r & 7);
        gwo[i]   = r * DM_ + cg * 8;
        ldswo[i] = (wave * 256 + i * 64) * 8;
    }
#pragma unroll
    for (int i = 0; i < 2; i++) {
        int g = wave * 128 + i * 64 + lane;       // 0..511
        int r = g >> 3, cg = (g & 7) ^ (r & 7);
        gao[i]   = r * DM_ + cg * 8;
        ldsao[i] = (wave * 128 + i * 64) * 8;
    }
    const u16* Wp = W + (size_t)n0 * DM_;
    const u16* Ap = A + (size_t)m0 * DM_;

    floatx4 acc[2][4];
#pragma unroll
    for (int i = 0; i < 2; i++)
#pragma unroll
        for (int j = 0; j < 4; j++) acc[i][j] = (floatx4){0.f, 0.f, 0.f, 0.f};

    for (int k0 = 0; k0 < DM_; k0 += 64) {
        __syncthreads();
#pragma unroll
        for (int i = 0; i < 4; i++)
            load_lds16(Wp + k0 + gwo[i], &Ws[ldswo[i]]);
#pragma unroll
        for (int i = 0; i < 2; i++)
            load_lds16(Ap + k0 + gao[i], &As[ldsao[i]]);
        drain_vm();                               // DMA data LDS-visible
        __syncthreads();

#pragma unroll
        for (int ks = 0; ks < 2; ks++) {
            short8 af[2], bf[4];
#pragma unroll
            for (int rt = 0; rt < 2; rt++)
                af[rt] = *(const short8*)&As[sw_off(wm * 32 + rt * 16 + n16, ks * 4 + quad)];
#pragma unroll
            for (int ct = 0; ct < 4; ct++)
                bf[ct] = *(const short8*)&Ws[sw_off(wn * 64 + ct * 16 + n16, ks * 4 + quad)];
#pragma unroll
            for (int rt = 0; rt < 2; rt++)
#pragma unroll
                for (int ct = 0; ct < 4; ct++)
                    acc[rt][ct] = __builtin_amdgcn_mfma_f32_16x16x32_bf16(
                        af[rt], bf[ct], acc[rt][ct], 0, 0, 0);
        }
    }

#pragma unroll
    for (int rt = 0; rt < 2; rt++)
#pragma unroll
        for (int ct = 0; ct < 4; ct++) {
            const int col = n0 + wn * 64 + ct * 16 + n16;
#pragma unroll
            for (int r = 0; r < 4; r++) {
                const int row = m0 + wm * 32 + rt * 16 + quad * 4 + r;
                Cf[(size_t)row * DM_ + col] = acc[rt][ct][r] + resid[(size_t)row * DM_ + col];
            }
        }
}

// =====================================================================
// LayerNorm in-place on [M, DM] rows. grid: M, block: 256 (R12-proven)
// =====================================================================
__global__ __launch_bounds__(256) void ln_kernel(
    float* __restrict__ io, const float* __restrict__ g, const float* __restrict__ bb)
{
    const int row = blockIdx.x, t = threadIdx.x;
    float* p = io + (size_t)row * DM_;
    float x[3];
    float sum = 0.0f, sq = 0.0f;
#pragma unroll
    for (int i = 0; i < 3; i++) {
        x[i] = p[t + i * 256];
        sum += x[i];
        sq  = fmaf(x[i], x[i], sq);
    }
#pragma unroll
    for (int off = 32; off >= 1; off >>= 1) {
        sum += __shfl_xor(sum, off);
        sq  += __shfl_xor(sq, off);
    }
    __shared__ float s1[4], s2[4];
    if ((t & 63) == 0) { s1[t >> 6] = sum; s2[t >> 6] = sq; }
    __syncthreads();
    sum = s1[0] + s1[1] + s1[2] + s1[3];
    sq  = s2[0] + s2[1] + s2[2] + s2[3];
    const float mu  = sum * (1.0f / 768.0f);
    const float var = sq * (1.0f / 768.0f) - mu * mu;
    const float rs  = rsqrtf(var + 1e-12f);
#pragma unroll
    for (int i = 0; i < 3; i++) {
        const int c = t + i * 256;
        p[c] = (x[i] - mu) * rs * g[c] + bb[c];
    }
}

// =====================================================================
// Workspace (bf16 elem offsets; total ~55.5 MB <= proven 75.5 MB):
//   Hb [0,R)      -> O (final attn out, bf16) overlays after gemm_qkv
//   Wb [R, R+4W)
//   Qh, Kh, Vt    (R each)
// =====================================================================
extern "C" void kernel_launch(void* const* d_in, const int* in_sizes, int n_in,
                              void* d_out, int out_size, void* d_ws, size_t ws_size,
                              hipStream_t stream)
{
    const float* hidden = (const float*)d_in[0];
    const float* cosT   = (const float*)d_in[1];
    const float* sinT   = (const float*)d_in[2];
    const float* Wq     = (const float*)d_in[3];
    const float* bq     = (const float*)d_in[4];
    const float* Wk     = (const float*)d_in[5];
    const float* bk     = (const float*)d_in[6];
    const float* Wv     = (const float*)d_in[7];
    const float* bv     = (const float*)d_in[8];
    const float* Wo     = (const float*)d_in[9];
    const float* ln_g   = (const float*)d_in[10];
    const float* ln_b   = (const float*)d_in[11];
    float* out = (float*)d_out;

    u16* wsb = (u16*)d_ws;
    u16* Hb  = wsb;
    u16* Wb  = wsb + ROWELEMS;
    u16* Qh  = Wb + 4 * WELEMS;
    u16* Kh  = Qh + ROWELEMS;
    u16* Vt  = Kh + ROWELEMS;
    u16* Ob  = Hb;                        // overlays Hb (dead after gemm_qkv)
    u16* Wqb = Wb, *Wkb = Wb + WELEMS, *Wvb = Wb + 2 * WELEMS, *Wob = Wb + 3 * WELEMS;

    conv_bf16<<<dim3(1024, 5), 256, 0, stream>>>(hidden, Wq, Wk, Wv, Wo, Hb, Wb);

    gemm_qkv<<<dim3(DM_ / 192, M_ / 128, 3), 256, 0, stream>>>(
        Hb, Wqb, Wkb, Wvb, bq, bk, bv, cosT, sinT, Qh, Kh, Vt);

    flash_mfma<<<dim3(S_ / 128, B_ * H_), 256, 0, stream>>>(Qh, Kh, Vt, Ob);

    gemm_out<<<dim3(DM_ / 128, M_ / 64), 256, 0, stream>>>(Ob, Wob, hidden, out);

    ln_kernel<<<M_, 256, 0, stream>>>(out, ln_g, ln_b);
}